// Round 3
// baseline (894.265 us; speedup 1.0000x reference)
//
#include <hip/hip_runtime.h>
#include <cstddef>

namespace {
constexpr int kB = 16;
constexpr int kN = 2048;
constexpr int kD = 256;   // D_IN
constexpr int kC = 32;
constexpr int kH = 64;
constexpr int kHeads = 4;
constexpr int kKD = 64;
constexpr int kChunks = 64;                      // n-chunks per b
constexpr int kRowsPerChunk = kN / kChunks;      // 32
constexpr int kTileR = 16;                       // rows per LDS tile
constexpr int kTiles = kRowsPerChunk / kTileR;   // 2

// workspace offsets (floats)
constexpr size_t OFF_XPART = 0;                      // [B,16,D]          65536
constexpr size_t OFF_V     = OFF_XPART + 65536;      // [B,C,H]           32768
constexpr size_t OFF_WV    = OFF_V + 32768;          // [B,C,D]          131072
constexpr size_t OFF_BV    = OFF_WV + 131072;        // [B,C]               512
constexpr size_t OFF_Y     = OFF_BV + 512;           // [B,C,D] (atomic) 131072
constexpr size_t OFF_CS    = OFF_Y + 131072;         // [B,C]               512
constexpr size_t OFF_CSP   = OFF_CS + 512;           // [B,chunks,C]      32768
constexpr size_t OFF_YP    = OFF_CSP + 32768;        // [B,chunks,C,D]  8388608
constexpr size_t WS_NEED_PARTIAL = (OFF_YP + 8388608) * sizeof(float);
}  // namespace

// ---- K1: xpart[b,j,d] = sum_{n in 128-row chunk j} x[b,n,d]
__global__ __launch_bounds__(256) void k_xpart(const float* __restrict__ x,
                                               float* __restrict__ xpart) {
  const int b = blockIdx.x, j = blockIdx.y, d = threadIdx.x;
  const float* xp = x + ((size_t)b * kN + (size_t)j * 128) * kD + d;
  float s = 0.f;
#pragma unroll 8
  for (int n = 0; n < 128; ++n) s += xp[(size_t)n * kD];
  xpart[((size_t)b * 16 + j) * kD + d] = s;
}

// ---- k_sv: s = y·W[c] + cs*b_caps[c]; v = squash(s); optional Wv (+)= W[c]·v, bv (+)= b_caps·v
// 256 threads: 4 waves split the 256-d GEMV; wave0 finishes squash.
__global__ __launch_bounds__(256) void k_sv(
    const float* __restrict__ W, const float* __restrict__ b_caps,
    const float* __restrict__ xpart, const float* __restrict__ y,
    const float* __restrict__ csum, const float* __restrict__ ypart,
    const float* __restrict__ cspart, float* __restrict__ v,
    float* __restrict__ Wv, float* __restrict__ bv,
    const int mode, const int computeWv, const int accWv, const int npart) {
  const int bc = blockIdx.x, b = bc >> 5, c = bc & 31;
  const int t = threadIdx.x;
  const int w = t >> 6, h = t & 63;
  __shared__ float yL[kD];
  __shared__ float sL[4][kH];
  __shared__ float vL[kH];
  __shared__ float csLs;

  if (mode == 0) {
    float s = 0.f;
#pragma unroll
    for (int j = 0; j < 16; ++j) s += xpart[((size_t)b * 16 + j) * kD + t];
    yL[t] = s * (1.f / (float)kC);
    if (t == 0) csLs = (float)kN / (float)kC;
  } else if (npart > 0) {
    float s = 0.f;
#pragma unroll 8
    for (int ch = 0; ch < kChunks; ++ch)
      s += ypart[(((size_t)b * kChunks + ch) * kC + c) * kD + t];
    yL[t] = s;
    if (t < 64) {
      float cs_ = cspart[((size_t)b * kChunks + t) * kC + c];
#pragma unroll
      for (int off = 32; off; off >>= 1) cs_ += __shfl_xor(cs_, off, 64);
      if (t == 0) csLs = cs_;
    }
  } else {
    yL[t] = y[(size_t)bc * kD + t];
    if (t == 0) csLs = csum[bc];
  }
  __syncthreads();

  const float* Wc = W + (size_t)c * kD * kH;
  {
    float acc = 0.f;
#pragma unroll 8
    for (int d = w * 64; d < (w + 1) * 64; ++d)
      acc = fmaf(yL[d], Wc[(size_t)d * kH + h], acc);
    sL[w][h] = acc;
  }
  __syncthreads();

  if (t < 64) {
    const float bch = b_caps[c * kH + h];
    float s = sL[0][h] + sL[1][h] + sL[2][h] + sL[3][h] + csLs * bch;
    float s2 = s * s;
#pragma unroll
    for (int off = 32; off; off >>= 1) s2 += __shfl_xor(s2, off, 64);
    const float scale = s2 / (1.f + s2) * rsqrtf(s2 + 1e-7f);
    const float vh = scale * s;
    v[(size_t)bc * kH + h] = vh;
    vL[h] = vh;
    if (computeWv) {
      float bvp = bch * vh;
#pragma unroll
      for (int off = 32; off; off >>= 1) bvp += __shfl_xor(bvp, off, 64);
      if (h == 0) bv[bc] = accWv ? (bv[bc] + bvp) : bvp;
    }
  }
  __syncthreads();
  if (computeWv) {
    // thread t handles output d = t
    float acc = 0.f;
    const float* Wrow = Wc + (size_t)t * kH;
#pragma unroll 8
    for (int hh = 0; hh < kH; ++hh) acc = fmaf(Wrow[hh], vL[hh], acc);
    Wv[(size_t)bc * kD + t] = accWv ? (Wv[(size_t)bc * kD + t] + acc) : acc;
  }
}

// ---- k_route: tiled routing pass. Block = (b, 32-row chunk); 2 tiles of 16 rows.
__global__ __launch_bounds__(256, 4) void k_route(
    const float* __restrict__ x, const float* __restrict__ Wv,
    const float* __restrict__ bv, float* __restrict__ y,
    float* __restrict__ csum, float* __restrict__ ypart,
    float* __restrict__ cspart, const int usePart) {
  const int b = blockIdx.x, chunk = blockIdx.y;
  const int t = threadIdx.x;
  const int c = t & 31, seg = t >> 5;   // capsule, 32-wide d-segment (0..7)
  const int w = t >> 6;                 // wave (0..3)
  __shared__ float xs[kTileR][kD];      // 16 KB
  __shared__ float aL[4][kTileR][kC];   // 8 KB
  __shared__ float pL[kTileR][kC];      // 2 KB
  __shared__ float csL[8][kC];          // 1 KB

  float wv[32];
  {
    const float4* p = reinterpret_cast<const float4*>(
        Wv + ((size_t)(b * kC + c)) * kD + seg * 32);
#pragma unroll
    for (int j = 0; j < 8; ++j) {
      float4 q = p[j];
      wv[4 * j] = q.x; wv[4 * j + 1] = q.y; wv[4 * j + 2] = q.z; wv[4 * j + 3] = q.w;
    }
  }
  const float bvreg = bv[b * kC + c];
  float yreg[32];
#pragma unroll
  for (int i = 0; i < 32; ++i) yreg[i] = 0.f;
  float csreg = 0.f;

  const int n0 = chunk * kRowsPerChunk;
  float4 xf[4];
  {
    const float4* xg = reinterpret_cast<const float4*>(x + ((size_t)b * kN + n0) * kD);
#pragma unroll
    for (int j = 0; j < 4; ++j) xf[j] = xg[t + 256 * j];
  }

#pragma unroll
  for (int tile = 0; tile < kTiles; ++tile) {
    __syncthreads();  // previous tile's xs readers done
    {
      float4* xs4 = reinterpret_cast<float4*>(&xs[0][0]);
#pragma unroll
      for (int j = 0; j < 4; ++j) xs4[t + 256 * j] = xf[j];
    }
    __syncthreads();  // xs visible
    if (tile + 1 < kTiles) {
      const float4* xg = reinterpret_cast<const float4*>(
          x + ((size_t)b * kN + n0 + (tile + 1) * kTileR) * kD);
#pragma unroll
      for (int j = 0; j < 4; ++j) xf[j] = xg[t + 256 * j];
    }
    // A phase: partial logits on this thread's 32-wide d-slice
#pragma unroll
    for (int g = 0; g < 2; ++g) {
      float ar[8];
#pragma unroll
      for (int r8 = 0; r8 < 8; ++r8) {
        const int r = g * 8 + r8;
        const float4* xv = reinterpret_cast<const float4*>(&xs[r][seg * 32]);
        float acc = 0.f;
#pragma unroll
        for (int j = 0; j < 8; ++j) {
          float4 q = xv[j];  // broadcast within half-wave
          acc = fmaf(wv[4 * j], q.x, acc);
          acc = fmaf(wv[4 * j + 1], q.y, acc);
          acc = fmaf(wv[4 * j + 2], q.z, acc);
          acc = fmaf(wv[4 * j + 3], q.w, acc);
        }
        ar[r8] = acc;
      }
#pragma unroll
      for (int r8 = 0; r8 < 8; ++r8) {
        ar[r8] += __shfl_xor(ar[r8], 32);  // combine seg pair within wave
        if ((t & 32) == 0) aL[w][g * 8 + r8][c] = ar[r8];
      }
    }
    __syncthreads();  // aL visible
    // softmax: thread (c,seg) handles rows seg*2+k  (shfl widths <=16: stays within half-wave = one row)
#pragma unroll
    for (int k = 0; k < 2; ++k) {
      const int r = seg * 2 + k;
      float L = bvreg;
#pragma unroll
      for (int j = 0; j < 4; ++j) L += aL[j][r][c];
      float m = L;
#pragma unroll
      for (int off = 16; off; off >>= 1) m = fmaxf(m, __shfl_xor(m, off, 64));
      const float e = __expf(L - m);
      float ssum = e;
#pragma unroll
      for (int off = 16; off; off >>= 1) ssum += __shfl_xor(ssum, off, 64);
      const float p = e / ssum;
      pL[r][c] = p;
      csreg += p;
    }
    __syncthreads();  // pL visible
    // accumulate y
#pragma unroll 4
    for (int r = 0; r < kTileR; ++r) {
      const float p = pL[r][c];
      const float4* xv = reinterpret_cast<const float4*>(&xs[r][seg * 32]);
#pragma unroll
      for (int j = 0; j < 8; ++j) {
        float4 q = xv[j];
        yreg[4 * j] = fmaf(p, q.x, yreg[4 * j]);
        yreg[4 * j + 1] = fmaf(p, q.y, yreg[4 * j + 1]);
        yreg[4 * j + 2] = fmaf(p, q.z, yreg[4 * j + 2]);
        yreg[4 * j + 3] = fmaf(p, q.w, yreg[4 * j + 3]);
      }
    }
  }
  // flush
  csL[seg][c] = csreg;
  __syncthreads();
  if (usePart) {
    float4* yp = reinterpret_cast<float4*>(
        ypart + (((size_t)b * kChunks + chunk) * kC + c) * kD + seg * 32);
#pragma unroll
    for (int j = 0; j < 8; ++j) {
      float4 q;
      q.x = yreg[4 * j]; q.y = yreg[4 * j + 1];
      q.z = yreg[4 * j + 2]; q.w = yreg[4 * j + 3];
      yp[j] = q;
    }
    if (t < 32) {
      float s = 0.f;
#pragma unroll
      for (int j = 0; j < 8; ++j) s += csL[j][t];
      cspart[((size_t)b * kChunks + chunk) * kC + t] = s;
    }
  } else {
    float* yp = y + ((size_t)(b * kC + c)) * kD + seg * 32;
#pragma unroll
    for (int i = 0; i < 32; ++i) atomicAdd(yp + i, yreg[i]);
    if (t < 32) {
      float s = 0.f;
#pragma unroll
      for (int j = 0; j < 8; ++j) s += csL[j][t];
      atomicAdd(csum + b * kC + t, s);
    }
  }
}

// ---- k_attn: fused MHA + out-proj + residual + LN + squash*gamma, one block per b.
__global__ __launch_bounds__(256) void k_attn(
    const float* __restrict__ routed, const float* __restrict__ Wq,
    const float* __restrict__ bq, const float* __restrict__ Wk,
    const float* __restrict__ bk, const float* __restrict__ Wvp,
    const float* __restrict__ bvp, const float* __restrict__ Wo,
    const float* __restrict__ bo, const float* __restrict__ ln_g,
    const float* __restrict__ ln_b, const float* __restrict__ gamma,
    float* __restrict__ out) {
  const int b = blockIdx.x, t = threadIdx.x;
  __shared__ float rL[kC * kH];        // 8 KB
  __shared__ float qL[kC * kKD];       // 8 KB
  __shared__ float kL[kC][kKD + 1];    // padded: kills 32-way conflict in score phase
  __shared__ float vL2[kC * kKD];
  __shared__ float scL[kC][kC];
  __shared__ float ctxL[kC * kKD];
  float accO[8];
#pragma unroll
  for (int j = 0; j < 8; ++j) accO[j] = 0.f;
  for (int i = t; i < kC * kH; i += 256) rL[i] = routed[(size_t)b * kC * kH + i];
  __syncthreads();

  for (int head = 0; head < kHeads; ++head) {
    for (int e = t; e < kC * kKD; e += 256) {
      const int cc = e >> 6, kk = e & 63;
      float aq = bq[head * kKD + kk];
      float ak = bk[head * kKD + kk];
      float av = bvp[head * kKD + kk];
#pragma unroll 8
      for (int hh = 0; hh < kH; ++hh) {
        const float r = rL[cc * kH + hh];
        const int wi = (hh * kHeads + head) * kKD + kk;
        aq = fmaf(r, Wq[wi], aq);
        ak = fmaf(r, Wk[wi], ak);
        av = fmaf(r, Wvp[wi], av);
      }
      qL[e] = aq; kL[cc][kk] = ak; vL2[e] = av;
    }
    __syncthreads();
    for (int e = t; e < kC * kC; e += 256) {
      const int qc = e >> 5, kc = e & 31;
      float s = 0.f;
#pragma unroll 8
      for (int d = 0; d < kKD; ++d) s = fmaf(qL[qc * kKD + d], kL[kc][d], s);
      scL[qc][kc] = s * 0.125f;
    }
    __syncthreads();
    if (t < kC) {
      float m = -1e30f;
#pragma unroll
      for (int kc = 0; kc < kC; ++kc) m = fmaxf(m, scL[t][kc]);
      float ssum = 0.f;
#pragma unroll
      for (int kc = 0; kc < kC; ++kc) {
        const float e2 = __expf(scL[t][kc] - m);
        scL[t][kc] = e2;
        ssum += e2;
      }
      const float inv = 1.f / ssum;
#pragma unroll
      for (int kc = 0; kc < kC; ++kc) scL[t][kc] *= inv;
    }
    __syncthreads();
    for (int e = t; e < kC * kKD; e += 256) {
      const int qc = e >> 6, d = e & 63;
      float s = 0.f;
#pragma unroll 8
      for (int kc = 0; kc < kC; ++kc) s = fmaf(scL[qc][kc], vL2[kc * kKD + d], s);
      ctxL[e] = s;
    }
    __syncthreads();
    // accumulate out-projection: element e = t + 256*j → (qc = e>>6, h = e&63)
#pragma unroll
    for (int j = 0; j < 8; ++j) {
      const int e = t + 256 * j, qc = e >> 6, h = e & 63;
      float s = accO[j];
      const float* Wor = Wo + ((size_t)head * kKD) * kH + h;
#pragma unroll 8
      for (int d = 0; d < kKD; ++d) s = fmaf(ctxL[qc * kKD + d], Wor[(size_t)d * kH], s);
      accO[j] = s;
    }
    __syncthreads();  // ctxL/qL reads done before next head overwrites
  }
  // final: residual + LN + squash. Wave w's lanes cover h=0..63 for qc = w+4j.
  const float g0 = gamma[0];
  const int h = t & 63;
  const float lg = ln_g[h], lb = ln_b[h], bh = bo[h];
#pragma unroll
  for (int j = 0; j < 8; ++j) {
    const int e = t + 256 * j;
    const float yv = accO[j] + bh + rL[e];
    float mu = yv;
#pragma unroll
    for (int off = 32; off; off >>= 1) mu += __shfl_xor(mu, off, 64);
    mu *= (1.f / (float)kH);
    const float dv = yv - mu;
    float var = dv * dv;
#pragma unroll
    for (int off = 32; off; off >>= 1) var += __shfl_xor(var, off, 64);
    var *= (1.f / (float)kH);
    const float nrm = dv * rsqrtf(var + 1e-3f) * lg + lb;
    float s2 = nrm * nrm;
#pragma unroll
    for (int off = 32; off; off >>= 1) s2 += __shfl_xor(s2, off, 64);
    const float scale = s2 / (1.f + s2) * rsqrtf(s2 + 1e-7f);
    out[(size_t)b * kC * kH + e] = scale * nrm * g0;
  }
}

extern "C" void kernel_launch(void* const* d_in, const int* in_sizes, int n_in,
                              void* d_out, int out_size, void* d_ws, size_t ws_size,
                              hipStream_t stream) {
  (void)in_sizes; (void)n_in; (void)out_size;
  const float* x      = (const float*)d_in[0];
  const float* W      = (const float*)d_in[1];
  const float* b_caps = (const float*)d_in[2];
  const float* gamma  = (const float*)d_in[3];
  const float* Wq     = (const float*)d_in[4];
  const float* bq     = (const float*)d_in[5];
  const float* Wk     = (const float*)d_in[6];
  const float* bk     = (const float*)d_in[7];
  const float* Wv_in  = (const float*)d_in[8];
  const float* bv_in  = (const float*)d_in[9];
  const float* Wo     = (const float*)d_in[10];
  const float* bo     = (const float*)d_in[11];
  const float* ln_g   = (const float*)d_in[12];
  const float* ln_b   = (const float*)d_in[13];
  float* out = (float*)d_out;
  float* ws  = (float*)d_ws;

  float* xpart = ws + OFF_XPART;
  float* v     = ws + OFF_V;
  float* Wv    = ws + OFF_WV;
  float* bv    = ws + OFF_BV;
  float* y     = ws + OFF_Y;
  float* cs    = ws + OFF_CS;
  float* csp   = ws + OFF_CSP;
  float* yp    = ws + OFF_YP;

  const int usePart = (ws_size >= WS_NEED_PARTIAL) ? 1 : 0;

  k_xpart<<<dim3(kB, 16), 256, 0, stream>>>(x, xpart);
  k_sv<<<kB * kC, 256, 0, stream>>>(W, b_caps, xpart, y, cs, yp, csp, v, Wv, bv,
                                    /*mode=*/0, /*computeWv=*/1, /*accWv=*/0, 0);

  if (!usePart) {
    hipMemsetAsync(y, 0, (size_t)kB * kC * kD * sizeof(float), stream);
    hipMemsetAsync(cs, 0, (size_t)kB * kC * sizeof(float), stream);
  }
  k_route<<<dim3(kB, kChunks), 256, 0, stream>>>(x, Wv, bv, y, cs, yp, csp, usePart);
  k_sv<<<kB * kC, 256, 0, stream>>>(W, b_caps, xpart, y, cs, yp, csp, v, Wv, bv,
                                    /*mode=*/1, /*computeWv=*/1, /*accWv=*/1,
                                    usePart ? kChunks : 0);

  if (!usePart) {
    hipMemsetAsync(y, 0, (size_t)kB * kC * kD * sizeof(float), stream);
    hipMemsetAsync(cs, 0, (size_t)kB * kC * sizeof(float), stream);
  }
  k_route<<<dim3(kB, kChunks), 256, 0, stream>>>(x, Wv, bv, y, cs, yp, csp, usePart);
  k_sv<<<kB * kC, 256, 0, stream>>>(W, b_caps, xpart, y, cs, yp, csp, v, Wv, bv,
                                    /*mode=*/1, /*computeWv=*/0, /*accWv=*/0,
                                    usePart ? kChunks : 0);

  k_attn<<<kB, 256, 0, stream>>>(v, Wq, bq, Wk, bk, Wv_in, bv_in, Wo, bo,
                                 ln_g, ln_b, gamma, out);
}

// Round 4
// 288.479 us; speedup vs baseline: 3.0999x; 3.0999x over previous
//
#include <hip/hip_runtime.h>
#include <cstddef>

namespace {
constexpr int kB = 16;
constexpr int kN = 2048;
constexpr int kD = 256;   // D_IN
constexpr int kC = 32;
constexpr int kH = 64;
constexpr int kHeads = 4;
constexpr int kKD = 64;
constexpr int kChunks = 32;                      // n-chunks per b (64 rows each)
constexpr int kRowsPerChunk = kN / kChunks;      // 64
constexpr int kTileR = 32;                       // rows per LDS tile
constexpr int kTiles = kRowsPerChunk / kTileR;   // 2

// workspace offsets (floats)
constexpr size_t OFF_XPART = 0;                      // [B,16,D]          65536
constexpr size_t OFF_V     = OFF_XPART + 65536;      // [B,C,H]           32768
constexpr size_t OFF_WV    = OFF_V + 32768;          // [B,C,D]          131072
constexpr size_t OFF_BV    = OFF_WV + 131072;        // [B,C]               512
constexpr size_t OFF_Y     = OFF_BV + 512;           // [B,C,D] (atomic) 131072
constexpr size_t OFF_CS    = OFF_Y + 131072;         // [B,C]               512
constexpr size_t OFF_CTX   = OFF_CS + 512;           // [B,C,HEADS,KD]   524288
constexpr size_t OFF_CSP   = OFF_CTX + 524288;       // [B,chunks,C]      16384
constexpr size_t OFF_YP    = OFF_CSP + 16384;        // [B,chunks,C,D]  4194304
constexpr size_t WS_NEED_PARTIAL = (OFF_YP + 4194304) * sizeof(float);
}  // namespace

// ---- k_xpart: xpart[b,j,d] = sum_{n in 128-row chunk j} x[b,n,d]
__global__ __launch_bounds__(256) void k_xpart(const float* __restrict__ x,
                                               float* __restrict__ xpart) {
  const int b = blockIdx.x, j = blockIdx.y, d = threadIdx.x;
  const float* xp = x + ((size_t)b * kN + (size_t)j * 128) * kD + d;
  float s = 0.f;
#pragma unroll 8
  for (int n = 0; n < 128; ++n) s += xp[(size_t)n * kD];
  xpart[((size_t)b * 16 + j) * kD + d] = s;
}

// ---- k_sv: s = y·W[c] + cs*b_caps[c]; v = squash(s); optional Wv (+)= W[c]·v, bv (+)= b_caps·v
// 256 threads: 4 waves split the 256-d GEMV; wave0 finishes squash.
__global__ __launch_bounds__(256) void k_sv(
    const float* __restrict__ W, const float* __restrict__ b_caps,
    const float* __restrict__ xpart, const float* __restrict__ y,
    const float* __restrict__ csum, const float* __restrict__ ypart,
    const float* __restrict__ cspart, float* __restrict__ v,
    float* __restrict__ Wv, float* __restrict__ bv,
    const int mode, const int computeWv, const int accWv, const int npart) {
  const int bc = blockIdx.x, b = bc >> 5, c = bc & 31;
  const int t = threadIdx.x;
  const int w = t >> 6, h = t & 63;
  __shared__ float yL[kD];
  __shared__ float sL[4][kH];
  __shared__ float vL[kH];
  __shared__ float csLs;

  if (mode == 0) {
    float s = 0.f;
#pragma unroll
    for (int j = 0; j < 16; ++j) s += xpart[((size_t)b * 16 + j) * kD + t];
    yL[t] = s * (1.f / (float)kC);
    if (t == 0) csLs = (float)kN / (float)kC;
  } else if (npart > 0) {
    float s = 0.f;
#pragma unroll 8
    for (int ch = 0; ch < kChunks; ++ch)
      s += ypart[(((size_t)b * kChunks + ch) * kC + c) * kD + t];
    yL[t] = s;
    if (t < 32) {
      float cs_ = cspart[((size_t)b * kChunks + t) * kC + c];
#pragma unroll
      for (int off = 16; off; off >>= 1) cs_ += __shfl_xor(cs_, off, 64);
      if (t == 0) csLs = cs_;
    }
  } else {
    yL[t] = y[(size_t)bc * kD + t];
    if (t == 0) csLs = csum[bc];
  }
  __syncthreads();

  const float* Wc = W + (size_t)c * kD * kH;
  {
    float acc = 0.f;
#pragma unroll 8
    for (int d = w * 64; d < (w + 1) * 64; ++d)
      acc = fmaf(yL[d], Wc[(size_t)d * kH + h], acc);
    sL[w][h] = acc;
  }
  __syncthreads();

  if (t < 64) {
    const float bch = b_caps[c * kH + h];
    float s = sL[0][h] + sL[1][h] + sL[2][h] + sL[3][h] + csLs * bch;
    float s2 = s * s;
#pragma unroll
    for (int off = 32; off; off >>= 1) s2 += __shfl_xor(s2, off, 64);
    const float scale = s2 / (1.f + s2) * rsqrtf(s2 + 1e-7f);
    const float vh = scale * s;
    v[(size_t)bc * kH + h] = vh;
    vL[h] = vh;
    if (computeWv) {
      float bvp = bch * vh;
#pragma unroll
      for (int off = 32; off; off >>= 1) bvp += __shfl_xor(bvp, off, 64);
      if (h == 0) bv[bc] = accWv ? (bv[bc] + bvp) : bvp;
    }
  }
  __syncthreads();
  if (computeWv) {
    float acc = 0.f;
    const float* Wrow = Wc + (size_t)t * kH;
#pragma unroll 8
    for (int hh = 0; hh < kH; ++hh) acc = fmaf(Wrow[hh], vL[hh], acc);
    Wv[(size_t)bc * kD + t] = accWv ? (Wv[(size_t)bc * kD + t] + acc) : acc;
  }
}

// ---- k_route: tiled routing pass (round-2 structure: NO register cap).
// Block = (b, 64-row chunk); 2 tiles of 32 rows.
__global__ __launch_bounds__(256) void k_route(
    const float* __restrict__ x, const float* __restrict__ Wv,
    const float* __restrict__ bv, float* __restrict__ y,
    float* __restrict__ csum, float* __restrict__ ypart,
    float* __restrict__ cspart, const int usePart) {
  const int b = blockIdx.x, chunk = blockIdx.y;
  const int t = threadIdx.x;
  const int c = t & 31, seg = t >> 5;   // capsule, 32-wide d-segment (0..7)
  const int w = t >> 6;                 // wave (0..3)
  __shared__ float xs[kTileR][kD];      // 32 KB
  __shared__ float aL[4][kTileR][kC];   // 16 KB
  __shared__ float pL[kTileR][kC];      // 4 KB
  __shared__ float csL[8][kC];          // 1 KB

  float wv[32];
  {
    const float4* p = reinterpret_cast<const float4*>(
        Wv + ((size_t)(b * kC + c)) * kD + seg * 32);
#pragma unroll
    for (int j = 0; j < 8; ++j) {
      float4 q = p[j];
      wv[4 * j] = q.x; wv[4 * j + 1] = q.y; wv[4 * j + 2] = q.z; wv[4 * j + 3] = q.w;
    }
  }
  const float bvreg = bv[b * kC + c];
  float yreg[32];
#pragma unroll
  for (int i = 0; i < 32; ++i) yreg[i] = 0.f;
  float csreg = 0.f;

  const int n0 = chunk * kRowsPerChunk;
  float4 xf[8];
  {
    const float4* xg = reinterpret_cast<const float4*>(x + ((size_t)b * kN + n0) * kD);
#pragma unroll
    for (int j = 0; j < 8; ++j) xf[j] = xg[t + 256 * j];
  }

#pragma unroll
  for (int tile = 0; tile < kTiles; ++tile) {
    __syncthreads();  // previous tile's xs readers done
    {
      float4* xs4 = reinterpret_cast<float4*>(&xs[0][0]);
#pragma unroll
      for (int j = 0; j < 8; ++j) xs4[t + 256 * j] = xf[j];
    }
    __syncthreads();  // xs visible
    if (tile + 1 < kTiles) {
      const float4* xg = reinterpret_cast<const float4*>(
          x + ((size_t)b * kN + n0 + (tile + 1) * kTileR) * kD);
#pragma unroll
      for (int j = 0; j < 8; ++j) xf[j] = xg[t + 256 * j];
    }
    // A phase: partial logits on this thread's 32-wide d-slice
#pragma unroll
    for (int g = 0; g < 4; ++g) {
      float ar[8];
#pragma unroll
      for (int r8 = 0; r8 < 8; ++r8) {
        const int r = g * 8 + r8;
        const float4* xv = reinterpret_cast<const float4*>(&xs[r][seg * 32]);
        float acc = 0.f;
#pragma unroll
        for (int j = 0; j < 8; ++j) {
          float4 q = xv[j];  // broadcast within half-wave
          acc = fmaf(wv[4 * j], q.x, acc);
          acc = fmaf(wv[4 * j + 1], q.y, acc);
          acc = fmaf(wv[4 * j + 2], q.z, acc);
          acc = fmaf(wv[4 * j + 3], q.w, acc);
        }
        ar[r8] = acc;
      }
#pragma unroll
      for (int r8 = 0; r8 < 8; ++r8) {
        ar[r8] += __shfl_xor(ar[r8], 32);  // combine seg pair within wave
        if ((t & 32) == 0) aL[w][g * 8 + r8][c] = ar[r8];
      }
    }
    __syncthreads();  // aL visible
    // softmax: thread (c,seg) handles rows seg*4+k
#pragma unroll
    for (int k = 0; k < 4; ++k) {
      const int r = seg * 4 + k;
      float L = bvreg;
#pragma unroll
      for (int j = 0; j < 4; ++j) L += aL[j][r][c];
      float m = L;
#pragma unroll
      for (int off = 16; off; off >>= 1) m = fmaxf(m, __shfl_xor(m, off, 64));
      const float e = __expf(L - m);
      float ssum = e;
#pragma unroll
      for (int off = 16; off; off >>= 1) ssum += __shfl_xor(ssum, off, 64);
      const float p = e / ssum;
      pL[r][c] = p;
      csreg += p;
    }
    __syncthreads();  // pL visible
    // accumulate y
#pragma unroll 4
    for (int r = 0; r < kTileR; ++r) {
      const float p = pL[r][c];
      const float4* xv = reinterpret_cast<const float4*>(&xs[r][seg * 32]);
#pragma unroll
      for (int j = 0; j < 8; ++j) {
        float4 q = xv[j];
        yreg[4 * j] = fmaf(p, q.x, yreg[4 * j]);
        yreg[4 * j + 1] = fmaf(p, q.y, yreg[4 * j + 1]);
        yreg[4 * j + 2] = fmaf(p, q.z, yreg[4 * j + 2]);
        yreg[4 * j + 3] = fmaf(p, q.w, yreg[4 * j + 3]);
      }
    }
  }
  // flush
  csL[seg][c] = csreg;
  __syncthreads();
  if (usePart) {
    float4* yp = reinterpret_cast<float4*>(
        ypart + (((size_t)b * kChunks + chunk) * kC + c) * kD + seg * 32);
#pragma unroll
    for (int j = 0; j < 8; ++j) {
      float4 q;
      q.x = yreg[4 * j]; q.y = yreg[4 * j + 1];
      q.z = yreg[4 * j + 2]; q.w = yreg[4 * j + 3];
      yp[j] = q;
    }
    if (t < 32) {
      float s = 0.f;
#pragma unroll
      for (int j = 0; j < 8; ++j) s += csL[j][t];
      cspart[((size_t)b * kChunks + chunk) * kC + t] = s;
    }
  } else {
    float* yp = y + ((size_t)(b * kC + c)) * kD + seg * 32;
#pragma unroll
    for (int i = 0; i < 32; ++i) atomicAdd(yp + i, yreg[i]);
    if (t < 32) {
      float s = 0.f;
#pragma unroll
      for (int j = 0; j < 8; ++j) s += csL[j][t];
      atomicAdd(csum + b * kC + t, s);
    }
  }
}

// ---- k_mha: per (b, head) self-attention over the 32 capsules (padded LDS).
__global__ __launch_bounds__(256) void k_mha(
    const float* __restrict__ routed, const float* __restrict__ Wq,
    const float* __restrict__ bq, const float* __restrict__ Wk,
    const float* __restrict__ bk, const float* __restrict__ Wvp,
    const float* __restrict__ bvp, float* __restrict__ ctx) {
  const int b = blockIdx.x, head = blockIdx.y, t = threadIdx.x;
  __shared__ float rL[kC * kH];
  __shared__ float qL[kC * kKD];
  __shared__ float kL[kC][kKD + 1];   // padded: kills 32-way conflict in score phase
  __shared__ float vL[kC * kKD];
  __shared__ float sc[kC][kC + 1];    // padded: kills 32-way conflict in softmax phase
  for (int i = t; i < kC * kH; i += 256) rL[i] = routed[(size_t)b * kC * kH + i];
  __syncthreads();
  for (int e = t; e < kC * kKD; e += 256) {
    const int cc = e >> 6, kk = e & 63;
    float aq = bq[head * kKD + kk];
    float ak = bk[head * kKD + kk];
    float av = bvp[head * kKD + kk];
#pragma unroll 8
    for (int hh = 0; hh < kH; ++hh) {
      const float r = rL[cc * kH + hh];
      const int wi = (hh * kHeads + head) * kKD + kk;
      aq = fmaf(r, Wq[wi], aq);
      ak = fmaf(r, Wk[wi], ak);
      av = fmaf(r, Wvp[wi], av);
    }
    qL[e] = aq; kL[cc][kk] = ak; vL[e] = av;
  }
  __syncthreads();
  for (int e = t; e < kC * kC; e += 256) {
    const int qc = e >> 5, kc = e & 31;
    float s = 0.f;
#pragma unroll 8
    for (int d = 0; d < kKD; ++d) s = fmaf(qL[qc * kKD + d], kL[kc][d], s);
    sc[qc][kc] = s * 0.125f;
  }
  __syncthreads();
  if (t < kC) {
    float m = -1e30f;
#pragma unroll
    for (int kc = 0; kc < kC; ++kc) m = fmaxf(m, sc[t][kc]);
    float ssum = 0.f;
#pragma unroll
    for (int kc = 0; kc < kC; ++kc) {
      const float e2 = __expf(sc[t][kc] - m);
      sc[t][kc] = e2;
      ssum += e2;
    }
    const float inv = 1.f / ssum;
#pragma unroll
    for (int kc = 0; kc < kC; ++kc) sc[t][kc] *= inv;
  }
  __syncthreads();
  for (int e = t; e < kC * kKD; e += 256) {
    const int qc = e >> 6, d = e & 63;
    float s = 0.f;
#pragma unroll 8
    for (int kc = 0; kc < kC; ++kc) s = fmaf(sc[qc][kc], vL[kc * kKD + d], s);
    ctx[(((size_t)b * kC + qc) * kHeads + head) * kKD + d] = s;
  }
}

// ---- k_final: out-proj + residual + LN + squash*gamma. Block = (b,c), 4 waves
// split the 256-dim contraction; wave 0 finishes.
__global__ __launch_bounds__(256) void k_final(
    const float* __restrict__ ctx, const float* __restrict__ Wo,
    const float* __restrict__ bo, const float* __restrict__ routed,
    const float* __restrict__ ln_g, const float* __restrict__ ln_b,
    const float* __restrict__ gamma, float* __restrict__ out) {
  const int bc = blockIdx.x, t = threadIdx.x;
  const int w = t >> 6, h = t & 63;
  __shared__ float cL[kHeads * kKD];
  __shared__ float sL[4][kH];
  cL[t] = ctx[(size_t)bc * (kHeads * kKD) + t];
  __syncthreads();
  float acc = 0.f;
#pragma unroll 8
  for (int nd = w * 64; nd < (w + 1) * 64; ++nd)
    acc = fmaf(cL[nd], Wo[(size_t)nd * kH + h], acc);
  sL[w][h] = acc;
  __syncthreads();
  if (t < 64) {
    const float yv = sL[0][h] + sL[1][h] + sL[2][h] + sL[3][h] + bo[h] +
                     routed[(size_t)bc * kH + h];
    float mu = yv;
#pragma unroll
    for (int off = 32; off; off >>= 1) mu += __shfl_xor(mu, off, 64);
    mu *= (1.f / (float)kH);
    const float dv = yv - mu;
    float var = dv * dv;
#pragma unroll
    for (int off = 32; off; off >>= 1) var += __shfl_xor(var, off, 64);
    var *= (1.f / (float)kH);
    const float nrm = dv * rsqrtf(var + 1e-3f) * ln_g[h] + ln_b[h];
    float s2 = nrm * nrm;
#pragma unroll
    for (int off = 32; off; off >>= 1) s2 += __shfl_xor(s2, off, 64);
    const float scale = s2 / (1.f + s2) * rsqrtf(s2 + 1e-7f);
    out[(size_t)bc * kH + h] = scale * nrm * gamma[0];
  }
}

extern "C" void kernel_launch(void* const* d_in, const int* in_sizes, int n_in,
                              void* d_out, int out_size, void* d_ws, size_t ws_size,
                              hipStream_t stream) {
  (void)in_sizes; (void)n_in; (void)out_size;
  const float* x      = (const float*)d_in[0];
  const float* W      = (const float*)d_in[1];
  const float* b_caps = (const float*)d_in[2];
  const float* gamma  = (const float*)d_in[3];
  const float* Wq     = (const float*)d_in[4];
  const float* bq     = (const float*)d_in[5];
  const float* Wk     = (const float*)d_in[6];
  const float* bk     = (const float*)d_in[7];
  const float* Wv_in  = (const float*)d_in[8];
  const float* bv_in  = (const float*)d_in[9];
  const float* Wo     = (const float*)d_in[10];
  const float* bo     = (const float*)d_in[11];
  const float* ln_g   = (const float*)d_in[12];
  const float* ln_b   = (const float*)d_in[13];
  float* out = (float*)d_out;
  float* ws  = (float*)d_ws;

  float* xpart = ws + OFF_XPART;
  float* v     = ws + OFF_V;
  float* Wv    = ws + OFF_WV;
  float* bv    = ws + OFF_BV;
  float* y     = ws + OFF_Y;
  float* cs    = ws + OFF_CS;
  float* ctx   = ws + OFF_CTX;
  float* csp   = ws + OFF_CSP;
  float* yp    = ws + OFF_YP;

  const int usePart = (ws_size >= WS_NEED_PARTIAL) ? 1 : 0;

  k_xpart<<<dim3(kB, 16), 256, 0, stream>>>(x, xpart);
  k_sv<<<kB * kC, 256, 0, stream>>>(W, b_caps, xpart, y, cs, yp, csp, v, Wv, bv,
                                    /*mode=*/0, /*computeWv=*/1, /*accWv=*/0, 0);

  if (!usePart) {
    hipMemsetAsync(y, 0, (size_t)kB * kC * kD * sizeof(float), stream);
    hipMemsetAsync(cs, 0, (size_t)kB * kC * sizeof(float), stream);
  }
  k_route<<<dim3(kB, kChunks), 256, 0, stream>>>(x, Wv, bv, y, cs, yp, csp, usePart);
  k_sv<<<kB * kC, 256, 0, stream>>>(W, b_caps, xpart, y, cs, yp, csp, v, Wv, bv,
                                    /*mode=*/1, /*computeWv=*/1, /*accWv=*/1,
                                    usePart ? kChunks : 0);

  if (!usePart) {
    hipMemsetAsync(y, 0, (size_t)kB * kC * kD * sizeof(float), stream);
    hipMemsetAsync(cs, 0, (size_t)kB * kC * sizeof(float), stream);
  }
  k_route<<<dim3(kB, kChunks), 256, 0, stream>>>(x, Wv, bv, y, cs, yp, csp, usePart);
  k_sv<<<kB * kC, 256, 0, stream>>>(W, b_caps, xpart, y, cs, yp, csp, v, Wv, bv,
                                    /*mode=*/1, /*computeWv=*/0, /*accWv=*/0,
                                    usePart ? kChunks : 0);

  k_mha<<<dim3(kB, kHeads), 256, 0, stream>>>(v, Wq, bq, Wk, bk, Wv_in, bv_in, ctx);
  k_final<<<kB * kC, 256, 0, stream>>>(ctx, Wo, bo, v, ln_g, ln_b, gamma, out);
}

// Round 5
// 264.451 us; speedup vs baseline: 3.3816x; 1.0909x over previous
//
#include <hip/hip_runtime.h>
#include <cstddef>

namespace {
constexpr int kB = 16;
constexpr int kN = 2048;
constexpr int kD = 256;   // D_IN
constexpr int kC = 32;
constexpr int kH = 64;
constexpr int kHeads = 4;
constexpr int kKD = 64;
constexpr int kChunks = 32;                      // n-chunks per b (64 rows each)
constexpr int kRowsPerChunk = kN / kChunks;      // 64
constexpr int kTileR = 32;                       // rows per LDS tile
constexpr int kTiles = kRowsPerChunk / kTileR;   // 2

// workspace offsets (floats)
constexpr size_t OFF_XPART = 0;                      // [B,16,D]            65536
constexpr size_t OFF_V     = OFF_XPART + 65536;      // [B,C,H]             32768
constexpr size_t OFF_WV    = OFF_V + 32768;          // [B,C,D]            131072
constexpr size_t OFF_BV    = OFF_WV + 131072;        // [B,C]                 512
constexpr size_t OFF_Y     = OFF_BV + 512;           // [B,C,D] (atomic)   131072
constexpr size_t OFF_CS    = OFF_Y + 131072;         // [B,C]                 512
constexpr size_t OFF_QKV   = OFF_CS + 512;           // [3,B,H,C,KD]       393216
constexpr size_t OFF_CTX   = OFF_QKV + 393216;       // [B,C,HEADS,KD]     524288
constexpr size_t OFF_CSP   = OFF_CTX + 524288;       // [B,chunks,C]        16384
constexpr size_t OFF_YP    = OFF_CSP + 16384;        // [B,chunks,C,D]    4194304
constexpr size_t WS_NEED_PARTIAL = (OFF_YP + 4194304) * sizeof(float);
}  // namespace

// ---- k_xpart: xpart[b,j,d] = sum_{n in 128-row chunk j} x[b,n,d]
__global__ __launch_bounds__(256) void k_xpart(const float* __restrict__ x,
                                               float* __restrict__ xpart) {
  const int b = blockIdx.x, j = blockIdx.y, d = threadIdx.x;
  const float* xp = x + ((size_t)b * kN + (size_t)j * 128) * kD + d;
  float s = 0.f;
#pragma unroll 8
  for (int n = 0; n < 128; ++n) s += xp[(size_t)n * kD];
  xpart[((size_t)b * 16 + j) * kD + d] = s;
}

// ---- k_sv: s = y·W[c] + cs*b_caps[c]; v = squash(s); optional Wv (+)= W[c]·v, bv (+)= b_caps·v
__global__ __launch_bounds__(256) void k_sv(
    const float* __restrict__ W, const float* __restrict__ b_caps,
    const float* __restrict__ xpart, const float* __restrict__ y,
    const float* __restrict__ csum, const float* __restrict__ ypart,
    const float* __restrict__ cspart, float* __restrict__ v,
    float* __restrict__ Wv, float* __restrict__ bv,
    const int mode, const int computeWv, const int accWv, const int npart) {
  const int bc = blockIdx.x, b = bc >> 5, c = bc & 31;
  const int t = threadIdx.x;
  const int w = t >> 6, h = t & 63;
  __shared__ float yL[kD];
  __shared__ float sL[4][kH];
  __shared__ float vL[kH];
  __shared__ float csLs;

  if (mode == 0) {
    float s = 0.f;
#pragma unroll
    for (int j = 0; j < 16; ++j) s += xpart[((size_t)b * 16 + j) * kD + t];
    yL[t] = s * (1.f / (float)kC);
    if (t == 0) csLs = (float)kN / (float)kC;
  } else if (npart > 0) {
    float s = 0.f;
#pragma unroll 8
    for (int ch = 0; ch < kChunks; ++ch)
      s += ypart[(((size_t)b * kChunks + ch) * kC + c) * kD + t];
    yL[t] = s;
    if (t < 32) {
      float cs_ = cspart[((size_t)b * kChunks + t) * kC + c];
#pragma unroll
      for (int off = 16; off; off >>= 1) cs_ += __shfl_xor(cs_, off, 64);
      if (t == 0) csLs = cs_;
    }
  } else {
    yL[t] = y[(size_t)bc * kD + t];
    if (t == 0) csLs = csum[bc];
  }
  __syncthreads();

  const float* Wc = W + (size_t)c * kD * kH;
  {
    float acc = 0.f;
#pragma unroll 8
    for (int d = w * 64; d < (w + 1) * 64; ++d)
      acc = fmaf(yL[d], Wc[(size_t)d * kH + h], acc);
    sL[w][h] = acc;
  }
  __syncthreads();

  if (t < 64) {
    const float bch = b_caps[c * kH + h];
    float s = sL[0][h] + sL[1][h] + sL[2][h] + sL[3][h] + csLs * bch;
    float s2 = s * s;
#pragma unroll
    for (int off = 32; off; off >>= 1) s2 += __shfl_xor(s2, off, 64);
    const float scale = s2 / (1.f + s2) * rsqrtf(s2 + 1e-7f);
    const float vh = scale * s;
    v[(size_t)bc * kH + h] = vh;
    vL[h] = vh;
    if (computeWv) {
      float bvp = bch * vh;
#pragma unroll
      for (int off = 32; off; off >>= 1) bvp += __shfl_xor(bvp, off, 64);
      if (h == 0) bv[bc] = accWv ? (bv[bc] + bvp) : bvp;
    }
  }
  __syncthreads();
  if (computeWv) {
    float acc = 0.f;
    const float* Wrow = Wc + (size_t)t * kH;
#pragma unroll 8
    for (int hh = 0; hh < kH; ++hh) acc = fmaf(Wrow[hh], vL[hh], acc);
    Wv[(size_t)bc * kD + t] = accWv ? (Wv[(size_t)bc * kD + t] + acc) : acc;
  }
}

// ---- k_route: tiled routing pass, 2-capsules-per-thread + row-split.
// Thread map: seg = t&7 (32-d slice), cp = (t>>3)&15 (caps {cp,cp+16}), rh = t>>7 (16-row half).
__global__ __launch_bounds__(256) void k_route(
    const float* __restrict__ x, const float* __restrict__ Wv,
    const float* __restrict__ bv, float* __restrict__ y,
    float* __restrict__ csum, float* __restrict__ ypart,
    float* __restrict__ cspart, const int usePart) {
  const int b = blockIdx.x, chunk = blockIdx.y;
  const int t = threadIdx.x;
  const int seg = t & 7, cp = (t >> 3) & 15, rh = t >> 7;
  const int smc = t & 31, sg = t >> 5;  // softmax mapping (capsule, row-group)

  __shared__ float xs[kTileR][kD];      // 32 KB (reused as combine scratch at flush)
  __shared__ float aL[kTileR][kC];      // 4 KB logits
  __shared__ float pL[kTileR][kC];      // 4 KB
  __shared__ float csL[8][kC];          // 1 KB

  // Wv slices for both capsules (32 d each)
  float wv0[32], wv1[32];
  {
    const float4* p0 = reinterpret_cast<const float4*>(
        Wv + ((size_t)(b * kC + cp)) * kD + seg * 32);
    const float4* p1 = reinterpret_cast<const float4*>(
        Wv + ((size_t)(b * kC + cp + 16)) * kD + seg * 32);
#pragma unroll
    for (int j = 0; j < 8; ++j) {
      float4 q0 = p0[j], q1 = p1[j];
      wv0[4 * j] = q0.x; wv0[4 * j + 1] = q0.y; wv0[4 * j + 2] = q0.z; wv0[4 * j + 3] = q0.w;
      wv1[4 * j] = q1.x; wv1[4 * j + 1] = q1.y; wv1[4 * j + 2] = q1.z; wv1[4 * j + 3] = q1.w;
    }
  }
  const float bvc = bv[b * kC + smc];   // bias added in softmax phase

  float y0[32], y1[32];
#pragma unroll
  for (int i = 0; i < 32; ++i) { y0[i] = 0.f; y1[i] = 0.f; }
  float csreg = 0.f;

  const int n0 = chunk * kRowsPerChunk;
  float4 xf[8];
  {
    const float4* xg = reinterpret_cast<const float4*>(x + ((size_t)b * kN + n0) * kD);
#pragma unroll
    for (int j = 0; j < 8; ++j) xf[j] = xg[t + 256 * j];
  }

#pragma unroll
  for (int tile = 0; tile < kTiles; ++tile) {
    __syncthreads();  // previous tile's xs readers done
    {
      float4* xs4 = reinterpret_cast<float4*>(&xs[0][0]);
#pragma unroll
      for (int j = 0; j < 8; ++j) xs4[t + 256 * j] = xf[j];
    }
    __syncthreads();  // xs visible
    if (tile + 1 < kTiles) {
      const float4* xg = reinterpret_cast<const float4*>(
          x + ((size_t)b * kN + n0 + (tile + 1) * kTileR) * kD);
#pragma unroll
      for (int j = 0; j < 8; ++j) xf[j] = xg[t + 256 * j];
    }
    // ---- A phase: rows rh*16..+15; each read serves both capsules.
#pragma unroll 4
    for (int r16 = 0; r16 < 16; ++r16) {
      const int r = rh * 16 + r16;
      const float4* xv = reinterpret_cast<const float4*>(&xs[r][seg * 32]);
      float a0 = 0.f, a1 = 0.f;
#pragma unroll
      for (int j = 0; j < 8; ++j) {
        float4 q = xv[j];
        a0 = fmaf(wv0[4 * j], q.x, a0); a1 = fmaf(wv1[4 * j], q.x, a1);
        a0 = fmaf(wv0[4 * j + 1], q.y, a0); a1 = fmaf(wv1[4 * j + 1], q.y, a1);
        a0 = fmaf(wv0[4 * j + 2], q.z, a0); a1 = fmaf(wv1[4 * j + 2], q.z, a1);
        a0 = fmaf(wv0[4 * j + 3], q.w, a0); a1 = fmaf(wv1[4 * j + 3], q.w, a1);
      }
      // reduce across the 8 seg lanes (low 3 bits of t)
#pragma unroll
      for (int off = 1; off < 8; off <<= 1) {
        a0 += __shfl_xor(a0, off, 64);
        a1 += __shfl_xor(a1, off, 64);
      }
      if (seg == 0) { aL[r][cp] = a0; aL[r][cp + 16] = a1; }
    }
    __syncthreads();  // aL visible
    // ---- softmax: thread (smc, sg) handles rows sg*4+k
#pragma unroll
    for (int k = 0; k < 4; ++k) {
      const int r = sg * 4 + k;
      float L = bvc + aL[r][smc];
      float m = L;
#pragma unroll
      for (int off = 16; off; off >>= 1) m = fmaxf(m, __shfl_xor(m, off, 64));
      const float e = __expf(L - m);
      float ssum = e;
#pragma unroll
      for (int off = 16; off; off >>= 1) ssum += __shfl_xor(ssum, off, 64);
      const float p = e / ssum;
      pL[r][smc] = p;
      csreg += p;
    }
    __syncthreads();  // pL visible
    // ---- accumulate y for both capsules over this thread's row half
#pragma unroll 4
    for (int r16 = 0; r16 < 16; ++r16) {
      const int r = rh * 16 + r16;
      const float pa = pL[r][cp];
      const float pb = pL[r][cp + 16];
      const float4* xv = reinterpret_cast<const float4*>(&xs[r][seg * 32]);
#pragma unroll
      for (int j = 0; j < 8; ++j) {
        float4 q = xv[j];
        y0[4 * j] = fmaf(pa, q.x, y0[4 * j]); y1[4 * j] = fmaf(pb, q.x, y1[4 * j]);
        y0[4 * j + 1] = fmaf(pa, q.y, y0[4 * j + 1]); y1[4 * j + 1] = fmaf(pb, q.y, y1[4 * j + 1]);
        y0[4 * j + 2] = fmaf(pa, q.z, y0[4 * j + 2]); y1[4 * j + 2] = fmaf(pb, q.z, y1[4 * j + 2]);
        y0[4 * j + 3] = fmaf(pa, q.w, y0[4 * j + 3]); y1[4 * j + 3] = fmaf(pb, q.w, y1[4 * j + 3]);
      }
    }
  }
  // ---- flush: combine rh halves via LDS scratch (xs reused), then write.
  csL[sg][smc] = csreg;
  __syncthreads();  // xs reads done + csL visible
  {
    float4* s4 = reinterpret_cast<float4*>(&xs[0][0]);
    const int lid = t & 127;
    if (rh == 1) {
#pragma unroll
      for (int j = 0; j < 8; ++j) {
        float4 q;
        q.x = y0[4 * j]; q.y = y0[4 * j + 1]; q.z = y0[4 * j + 2]; q.w = y0[4 * j + 3];
        s4[j * 128 + lid] = q;
      }
#pragma unroll
      for (int j = 0; j < 8; ++j) {
        float4 q;
        q.x = y1[4 * j]; q.y = y1[4 * j + 1]; q.z = y1[4 * j + 2]; q.w = y1[4 * j + 3];
        s4[(8 + j) * 128 + lid] = q;
      }
    }
    __syncthreads();
    if (rh == 0) {
#pragma unroll
      for (int j = 0; j < 8; ++j) {
        float4 q = s4[j * 128 + lid];
        y0[4 * j] += q.x; y0[4 * j + 1] += q.y; y0[4 * j + 2] += q.z; y0[4 * j + 3] += q.w;
      }
#pragma unroll
      for (int j = 0; j < 8; ++j) {
        float4 q = s4[(8 + j) * 128 + lid];
        y1[4 * j] += q.x; y1[4 * j + 1] += q.y; y1[4 * j + 2] += q.z; y1[4 * j + 3] += q.w;
      }
      if (usePart) {
        float4* yp0 = reinterpret_cast<float4*>(
            ypart + (((size_t)b * kChunks + chunk) * kC + cp) * kD + seg * 32);
        float4* yp1 = reinterpret_cast<float4*>(
            ypart + (((size_t)b * kChunks + chunk) * kC + cp + 16) * kD + seg * 32);
#pragma unroll
        for (int j = 0; j < 8; ++j) {
          float4 q;
          q.x = y0[4 * j]; q.y = y0[4 * j + 1]; q.z = y0[4 * j + 2]; q.w = y0[4 * j + 3];
          yp0[j] = q;
          q.x = y1[4 * j]; q.y = y1[4 * j + 1]; q.z = y1[4 * j + 2]; q.w = y1[4 * j + 3];
          yp1[j] = q;
        }
      } else {
        float* yp0 = y + ((size_t)(b * kC + cp)) * kD + seg * 32;
        float* yp1 = y + ((size_t)(b * kC + cp + 16)) * kD + seg * 32;
#pragma unroll
        for (int i = 0; i < 32; ++i) { atomicAdd(yp0 + i, y0[i]); atomicAdd(yp1 + i, y1[i]); }
      }
    }
    if (t < 32) {
      float s = 0.f;
#pragma unroll
      for (int j = 0; j < 8; ++j) s += csL[j][t];
      if (usePart) cspart[((size_t)b * kChunks + chunk) * kC + t] = s;
      else atomicAdd(csum + b * kC + t, s);
    }
  }
}

// ---- k_qkv: one projection per block. grid (B, HEADS, 3). W slice staged in LDS.
__global__ __launch_bounds__(256) void k_qkv(
    const float* __restrict__ routed, const float* __restrict__ Wq,
    const float* __restrict__ bq, const float* __restrict__ Wk,
    const float* __restrict__ bk, const float* __restrict__ Wvp,
    const float* __restrict__ bvp, float* __restrict__ qkv) {
  const int b = blockIdx.x, head = blockIdx.y, which = blockIdx.z;
  const int t = threadIdx.x;
  const float* Wsrc = (which == 0) ? Wq : (which == 1) ? Wk : Wvp;
  const float* bsrc = (which == 0) ? bq : (which == 1) ? bk : bvp;
  __shared__ float rL[kC * kH];        // 8 KB
  __shared__ float WL[kH][kKD + 1];    // padded
#pragma unroll
  for (int i = 0; i < 8; ++i) rL[t + 256 * i] = routed[(size_t)b * kC * kH + t + 256 * i];
#pragma unroll
  for (int i = 0; i < 16; ++i) {
    const int e = t + 256 * i, hh = e >> 6, kk = e & 63;
    WL[hh][kk] = Wsrc[((size_t)hh * kHeads + head) * kKD + kk];
  }
  __syncthreads();
#pragma unroll
  for (int i = 0; i < 8; ++i) {
    const int e = t + 256 * i, cc = e >> 6, kk = e & 63;
    float acc = bsrc[head * kKD + kk];
#pragma unroll 8
    for (int hh = 0; hh < kH; ++hh) acc = fmaf(rL[cc * kH + hh], WL[hh][kk], acc);
    qkv[((((size_t)which * kB + b) * kHeads + head) * kC + cc) * kKD + kk] = acc;
  }
}

// ---- k_attn2: scores + softmax + ctx from staged q/k/v. grid (B, HEADS).
__global__ __launch_bounds__(256) void k_attn2(const float* __restrict__ qkv,
                                               float* __restrict__ ctx) {
  const int b = blockIdx.x, head = blockIdx.y, t = threadIdx.x;
  constexpr size_t kWhichStride = (size_t)kB * kHeads * kC * kKD;
  const size_t base = ((size_t)b * kHeads + head) * kC * kKD;
  __shared__ float qL[kC][kKD];
  __shared__ float kL[kC][kKD + 1];
  __shared__ float vL[kC][kKD];
  __shared__ float sc[kC][kC + 1];
#pragma unroll
  for (int i = 0; i < 8; ++i) {
    const int e = t + 256 * i, cc = e >> 6, kk = e & 63;
    qL[cc][kk] = qkv[base + e];
    kL[cc][kk] = qkv[base + kWhichStride + e];
    vL[cc][kk] = qkv[base + 2 * kWhichStride + e];
  }
  __syncthreads();
#pragma unroll
  for (int i = 0; i < 4; ++i) {
    const int e = t + 256 * i, qc = e >> 5, kc = e & 31;
    float s = 0.f;
#pragma unroll 8
    for (int d = 0; d < kKD; ++d) s = fmaf(qL[qc][d], kL[kc][d], s);
    sc[qc][kc] = s * 0.125f;  // 1/sqrt(64)
  }
  __syncthreads();
  if (t < kC) {
    float m = -1e30f;
#pragma unroll
    for (int kc = 0; kc < kC; ++kc) m = fmaxf(m, sc[t][kc]);
    float ssum = 0.f;
#pragma unroll
    for (int kc = 0; kc < kC; ++kc) {
      const float e2 = __expf(sc[t][kc] - m);
      sc[t][kc] = e2;
      ssum += e2;
    }
    const float inv = 1.f / ssum;
#pragma unroll
    for (int kc = 0; kc < kC; ++kc) sc[t][kc] *= inv;
  }
  __syncthreads();
#pragma unroll
  for (int i = 0; i < 8; ++i) {
    const int e = t + 256 * i, qc = e >> 6, d = e & 63;
    float s = 0.f;
#pragma unroll 8
    for (int kc = 0; kc < kC; ++kc) s = fmaf(sc[qc][kc], vL[kc][d], s);
    ctx[(((size_t)b * kC + qc) * kHeads + head) * kKD + d] = s;
  }
}

// ---- k_final: out-proj + residual + LN + squash*gamma. Block = (b,c).
__global__ __launch_bounds__(256) void k_final(
    const float* __restrict__ ctx, const float* __restrict__ Wo,
    const float* __restrict__ bo, const float* __restrict__ routed,
    const float* __restrict__ ln_g, const float* __restrict__ ln_b,
    const float* __restrict__ gamma, float* __restrict__ out) {
  const int bc = blockIdx.x, t = threadIdx.x;
  const int w = t >> 6, h = t & 63;
  __shared__ float cL[kHeads * kKD];
  __shared__ float sL[4][kH];
  cL[t] = ctx[(size_t)bc * (kHeads * kKD) + t];
  __syncthreads();
  float acc = 0.f;
#pragma unroll 8
  for (int nd = w * 64; nd < (w + 1) * 64; ++nd)
    acc = fmaf(cL[nd], Wo[(size_t)nd * kH + h], acc);
  sL[w][h] = acc;
  __syncthreads();
  if (t < 64) {
    const float yv = sL[0][h] + sL[1][h] + sL[2][h] + sL[3][h] + bo[h] +
                     routed[(size_t)bc * kH + h];
    float mu = yv;
#pragma unroll
    for (int off = 32; off; off >>= 1) mu += __shfl_xor(mu, off, 64);
    mu *= (1.f / (float)kH);
    const float dv = yv - mu;
    float var = dv * dv;
#pragma unroll
    for (int off = 32; off; off >>= 1) var += __shfl_xor(var, off, 64);
    var *= (1.f / (float)kH);
    const float nrm = dv * rsqrtf(var + 1e-3f) * ln_g[h] + ln_b[h];
    float s2 = nrm * nrm;
#pragma unroll
    for (int off = 32; off; off >>= 1) s2 += __shfl_xor(s2, off, 64);
    const float scale = s2 / (1.f + s2) * rsqrtf(s2 + 1e-7f);
    out[(size_t)bc * kH + h] = scale * nrm * gamma[0];
  }
}

extern "C" void kernel_launch(void* const* d_in, const int* in_sizes, int n_in,
                              void* d_out, int out_size, void* d_ws, size_t ws_size,
                              hipStream_t stream) {
  (void)in_sizes; (void)n_in; (void)out_size;
  const float* x      = (const float*)d_in[0];
  const float* W      = (const float*)d_in[1];
  const float* b_caps = (const float*)d_in[2];
  const float* gamma  = (const float*)d_in[3];
  const float* Wq     = (const float*)d_in[4];
  const float* bq     = (const float*)d_in[5];
  const float* Wk     = (const float*)d_in[6];
  const float* bk     = (const float*)d_in[7];
  const float* Wv_in  = (const float*)d_in[8];
  const float* bv_in  = (const float*)d_in[9];
  const float* Wo     = (const float*)d_in[10];
  const float* bo     = (const float*)d_in[11];
  const float* ln_g   = (const float*)d_in[12];
  const float* ln_b   = (const float*)d_in[13];
  float* out = (float*)d_out;
  float* ws  = (float*)d_ws;

  float* xpart = ws + OFF_XPART;
  float* v     = ws + OFF_V;
  float* Wv    = ws + OFF_WV;
  float* bv    = ws + OFF_BV;
  float* y     = ws + OFF_Y;
  float* cs    = ws + OFF_CS;
  float* qkv   = ws + OFF_QKV;
  float* ctx   = ws + OFF_CTX;
  float* csp   = ws + OFF_CSP;
  float* yp    = ws + OFF_YP;

  const int usePart = (ws_size >= WS_NEED_PARTIAL) ? 1 : 0;

  k_xpart<<<dim3(kB, 16), 256, 0, stream>>>(x, xpart);
  k_sv<<<kB * kC, 256, 0, stream>>>(W, b_caps, xpart, y, cs, yp, csp, v, Wv, bv,
                                    /*mode=*/0, /*computeWv=*/1, /*accWv=*/0, 0);

  if (!usePart) {
    hipMemsetAsync(y, 0, (size_t)kB * kC * kD * sizeof(float), stream);
    hipMemsetAsync(cs, 0, (size_t)kB * kC * sizeof(float), stream);
  }
  k_route<<<dim3(kB, kChunks), 256, 0, stream>>>(x, Wv, bv, y, cs, yp, csp, usePart);
  k_sv<<<kB * kC, 256, 0, stream>>>(W, b_caps, xpart, y, cs, yp, csp, v, Wv, bv,
                                    /*mode=*/1, /*computeWv=*/1, /*accWv=*/1,
                                    usePart ? kChunks : 0);

  if (!usePart) {
    hipMemsetAsync(y, 0, (size_t)kB * kC * kD * sizeof(float), stream);
    hipMemsetAsync(cs, 0, (size_t)kB * kC * sizeof(float), stream);
  }
  k_route<<<dim3(kB, kChunks), 256, 0, stream>>>(x, Wv, bv, y, cs, yp, csp, usePart);
  k_sv<<<kB * kC, 256, 0, stream>>>(W, b_caps, xpart, y, cs, yp, csp, v, Wv, bv,
                                    /*mode=*/1, /*computeWv=*/0, /*accWv=*/0,
                                    usePart ? kChunks : 0);

  k_qkv<<<dim3(kB, kHeads, 3), 256, 0, stream>>>(v, Wq, bq, Wk, bk, Wv_in, bv_in, qkv);
  k_attn2<<<dim3(kB, kHeads), 256, 0, stream>>>(qkv, ctx);
  k_final<<<kB * kC, 256, 0, stream>>>(ctx, Wo, bo, v, ln_g, ln_b, gamma, out);
}

// Round 6
// 239.057 us; speedup vs baseline: 3.7408x; 1.1062x over previous
//
#include <hip/hip_runtime.h>
#include <cstddef>

namespace {
constexpr int kB = 16;
constexpr int kN = 2048;
constexpr int kD = 256;   // D_IN
constexpr int kC = 32;
constexpr int kH = 64;
constexpr int kHeads = 4;
constexpr int kKD = 64;
constexpr int kChunks = 32;                      // n-chunks per b (64 rows each)
constexpr int kRowsPerChunk = kN / kChunks;      // 64
constexpr int kTileR = 32;                       // rows per LDS tile
constexpr int kTiles = kRowsPerChunk / kTileR;   // 2

// workspace offsets (floats)
constexpr size_t OFF_XPART = 0;                      // [B,16,D]            65536
constexpr size_t OFF_V     = OFF_XPART + 65536;      // [B,C,H]             32768
constexpr size_t OFF_WV    = OFF_V + 32768;          // [B,C,D]            131072
constexpr size_t OFF_BV    = OFF_WV + 131072;        // [B,C]                 512
constexpr size_t OFF_Y     = OFF_BV + 512;           // [B,C,D] (atomic)   131072
constexpr size_t OFF_CS    = OFF_Y + 131072;         // [B,C]                 512
constexpr size_t OFF_CTX   = OFF_CS + 512;           // [B,C,HEADS,KD]     524288
constexpr size_t OFF_CSP   = OFF_CTX + 524288;       // [B,chunks,C]        16384
constexpr size_t OFF_YP    = OFF_CSP + 16384;        // [B,chunks,C,D]    4194304
constexpr size_t WS_NEED_PARTIAL = (OFF_YP + 4194304) * sizeof(float);
}  // namespace

// ---- k_xpart: xpart[b,j,d] = sum_{n in 128-row chunk j} x[b,n,d]
__global__ __launch_bounds__(256) void k_xpart(const float* __restrict__ x,
                                               float* __restrict__ xpart) {
  const int b = blockIdx.x, j = blockIdx.y, d = threadIdx.x;
  const float* xp = x + ((size_t)b * kN + (size_t)j * 128) * kD + d;
  float s = 0.f;
#pragma unroll 8
  for (int n = 0; n < 128; ++n) s += xp[(size_t)n * kD];
  xpart[((size_t)b * 16 + j) * kD + d] = s;
}

// ---- k_sv: s = y·W[c] + cs*b_caps[c]; v = squash(s); optional Wv (+)= W[c]·v, bv (+)= b_caps·v
__global__ __launch_bounds__(256) void k_sv(
    const float* __restrict__ W, const float* __restrict__ b_caps,
    const float* __restrict__ xpart, const float* __restrict__ y,
    const float* __restrict__ csum, const float* __restrict__ ypart,
    const float* __restrict__ cspart, float* __restrict__ v,
    float* __restrict__ Wv, float* __restrict__ bv,
    const int mode, const int computeWv, const int accWv, const int npart) {
  const int bc = blockIdx.x, b = bc >> 5, c = bc & 31;
  const int t = threadIdx.x;
  const int w = t >> 6, h = t & 63;
  __shared__ float yL[kD];
  __shared__ float sL[4][kH];
  __shared__ float vL[kH];
  __shared__ float csLs;

  if (mode == 0) {
    float s = 0.f;
#pragma unroll
    for (int j = 0; j < 16; ++j) s += xpart[((size_t)b * 16 + j) * kD + t];
    yL[t] = s * (1.f / (float)kC);
    if (t == 0) csLs = (float)kN / (float)kC;
  } else if (npart > 0) {
    float s = 0.f;
#pragma unroll 8
    for (int ch = 0; ch < kChunks; ++ch)
      s += ypart[(((size_t)b * kChunks + ch) * kC + c) * kD + t];
    yL[t] = s;
    if (t < 32) {
      float cs_ = cspart[((size_t)b * kChunks + t) * kC + c];
#pragma unroll
      for (int off = 16; off; off >>= 1) cs_ += __shfl_xor(cs_, off, 64);
      if (t == 0) csLs = cs_;
    }
  } else {
    yL[t] = y[(size_t)bc * kD + t];
    if (t == 0) csLs = csum[bc];
  }
  __syncthreads();

  const float* Wc = W + (size_t)c * kD * kH;
  {
    float acc = 0.f;
#pragma unroll 8
    for (int d = w * 64; d < (w + 1) * 64; ++d)
      acc = fmaf(yL[d], Wc[(size_t)d * kH + h], acc);
    sL[w][h] = acc;
  }
  __syncthreads();

  if (t < 64) {
    const float bch = b_caps[c * kH + h];
    float s = sL[0][h] + sL[1][h] + sL[2][h] + sL[3][h] + csLs * bch;
    float s2 = s * s;
#pragma unroll
    for (int off = 32; off; off >>= 1) s2 += __shfl_xor(s2, off, 64);
    const float scale = s2 / (1.f + s2) * rsqrtf(s2 + 1e-7f);
    const float vh = scale * s;
    v[(size_t)bc * kH + h] = vh;
    vL[h] = vh;
    if (computeWv) {
      float bvp = bch * vh;
#pragma unroll
      for (int off = 32; off; off >>= 1) bvp += __shfl_xor(bvp, off, 64);
      if (h == 0) bv[bc] = accWv ? (bv[bc] + bvp) : bvp;
    }
  }
  __syncthreads();
  if (computeWv) {
    float acc = 0.f;
    const float* Wrow = Wc + (size_t)t * kH;
#pragma unroll 8
    for (int hh = 0; hh < kH; ++hh) acc = fmaf(Wrow[hh], vL[hh], acc);
    Wv[(size_t)bc * kD + t] = accWv ? (Wv[(size_t)bc * kD + t] + acc) : acc;
  }
}

// ---- k_route: tiled routing, 2-caps/thread + row-split, XOR-swizzled xs.
// Thread map: seg = t&7 (32-d slice), cp = (t>>3)&15 (caps {cp,cp+16}), rh = t>>7.
// xs swizzle: logical float4 f -> physical (f & 0x38) | ((f + (f>>3)) & 7), so the
// 8 seg-broadcast reads per j hit 8 distinct bank quadruples (was: 8-way conflict).
__global__ __launch_bounds__(256) void k_route(
    const float* __restrict__ x, const float* __restrict__ Wv,
    const float* __restrict__ bv, float* __restrict__ y,
    float* __restrict__ csum, float* __restrict__ ypart,
    float* __restrict__ cspart, const int usePart) {
  const int b = blockIdx.x, chunk = blockIdx.y;
  const int t = threadIdx.x;
  const int seg = t & 7, cp = (t >> 3) & 15, rh = t >> 7;
  const int smc = t & 31, sg = t >> 5;  // softmax mapping (capsule, row-group)

  __shared__ float xs[kTileR][kD];      // 32 KB (swizzled; reused raw at flush)
  __shared__ float aL[kTileR][kC];      // 4 KB logits
  __shared__ float pL[kTileR][kC];      // 4 KB
  __shared__ float csL[8][kC];          // 1 KB

  float wv0[32], wv1[32];
  {
    const float4* p0 = reinterpret_cast<const float4*>(
        Wv + ((size_t)(b * kC + cp)) * kD + seg * 32);
    const float4* p1 = reinterpret_cast<const float4*>(
        Wv + ((size_t)(b * kC + cp + 16)) * kD + seg * 32);
#pragma unroll
    for (int j = 0; j < 8; ++j) {
      float4 q0 = p0[j], q1 = p1[j];
      wv0[4 * j] = q0.x; wv0[4 * j + 1] = q0.y; wv0[4 * j + 2] = q0.z; wv0[4 * j + 3] = q0.w;
      wv1[4 * j] = q1.x; wv1[4 * j + 1] = q1.y; wv1[4 * j + 2] = q1.z; wv1[4 * j + 3] = q1.w;
    }
  }
  const float bvc = bv[b * kC + smc];

  float y0[32], y1[32];
#pragma unroll
  for (int i = 0; i < 32; ++i) { y0[i] = 0.f; y1[i] = 0.f; }
  float csreg = 0.f;

  // per-thread constant: swizzled within-row float4 slot for staging stores
  const int f_log = t & 63;
  const int f_swz = (f_log & 0x38) | ((f_log + (f_log >> 3)) & 7);

  const int n0 = chunk * kRowsPerChunk;
  float4 xf[8];
  {
    const float4* xg = reinterpret_cast<const float4*>(x + ((size_t)b * kN + n0) * kD);
#pragma unroll
    for (int j = 0; j < 8; ++j) xf[j] = xg[t + 256 * j];
  }

#pragma unroll
  for (int tile = 0; tile < kTiles; ++tile) {
    __syncthreads();  // previous tile's xs readers done
    {
      float4* xs4 = reinterpret_cast<float4*>(&xs[0][0]);
#pragma unroll
      for (int j = 0; j < 8; ++j) xs4[(t & 0xC0) + 256 * j + f_swz] = xf[j];
    }
    __syncthreads();  // xs visible
    if (tile + 1 < kTiles) {
      const float4* xg = reinterpret_cast<const float4*>(
          x + ((size_t)b * kN + n0 + (tile + 1) * kTileR) * kD);
#pragma unroll
      for (int j = 0; j < 8; ++j) xf[j] = xg[t + 256 * j];
    }
    // ---- A phase: rows rh*16..+15; each (swizzled) read serves both capsules.
#pragma unroll 4
    for (int r16 = 0; r16 < 16; ++r16) {
      const int r = rh * 16 + r16;
      const float4* rowp = reinterpret_cast<const float4*>(&xs[0][0]) + r * 64 + seg * 8;
      float a0 = 0.f, a1 = 0.f;
#pragma unroll
      for (int j = 0; j < 8; ++j) {
        float4 q = rowp[(j + seg) & 7];   // swizzled slot for logical j
        a0 = fmaf(wv0[4 * j], q.x, a0); a1 = fmaf(wv1[4 * j], q.x, a1);
        a0 = fmaf(wv0[4 * j + 1], q.y, a0); a1 = fmaf(wv1[4 * j + 1], q.y, a1);
        a0 = fmaf(wv0[4 * j + 2], q.z, a0); a1 = fmaf(wv1[4 * j + 2], q.z, a1);
        a0 = fmaf(wv0[4 * j + 3], q.w, a0); a1 = fmaf(wv1[4 * j + 3], q.w, a1);
      }
#pragma unroll
      for (int off = 1; off < 8; off <<= 1) {
        a0 += __shfl_xor(a0, off, 64);
        a1 += __shfl_xor(a1, off, 64);
      }
      if (seg == 0) { aL[r][cp] = a0; aL[r][cp + 16] = a1; }
    }
    __syncthreads();  // aL visible
    // ---- softmax: thread (smc, sg) handles rows sg*4+k
#pragma unroll
    for (int k = 0; k < 4; ++k) {
      const int r = sg * 4 + k;
      float L = bvc + aL[r][smc];
      float m = L;
#pragma unroll
      for (int off = 16; off; off >>= 1) m = fmaxf(m, __shfl_xor(m, off, 64));
      const float e = __expf(L - m);
      float ssum = e;
#pragma unroll
      for (int off = 16; off; off >>= 1) ssum += __shfl_xor(ssum, off, 64);
      const float p = e / ssum;
      pL[r][smc] = p;
      csreg += p;
    }
    __syncthreads();  // pL visible
    // ---- accumulate y for both capsules over this thread's row half
#pragma unroll 4
    for (int r16 = 0; r16 < 16; ++r16) {
      const int r = rh * 16 + r16;
      const float pa = pL[r][cp];
      const float pb = pL[r][cp + 16];
      const float4* rowp = reinterpret_cast<const float4*>(&xs[0][0]) + r * 64 + seg * 8;
#pragma unroll
      for (int j = 0; j < 8; ++j) {
        float4 q = rowp[(j + seg) & 7];
        y0[4 * j] = fmaf(pa, q.x, y0[4 * j]); y1[4 * j] = fmaf(pb, q.x, y1[4 * j]);
        y0[4 * j + 1] = fmaf(pa, q.y, y0[4 * j + 1]); y1[4 * j + 1] = fmaf(pb, q.y, y1[4 * j + 1]);
        y0[4 * j + 2] = fmaf(pa, q.z, y0[4 * j + 2]); y1[4 * j + 2] = fmaf(pb, q.z, y1[4 * j + 2]);
        y0[4 * j + 3] = fmaf(pa, q.w, y0[4 * j + 3]); y1[4 * j + 3] = fmaf(pb, q.w, y1[4 * j + 3]);
      }
    }
  }
  // ---- flush: combine rh halves via LDS scratch (xs reused, raw indices).
  csL[sg][smc] = csreg;
  __syncthreads();
  {
    float4* s4 = reinterpret_cast<float4*>(&xs[0][0]);
    const int lid = t & 127;
    if (rh == 1) {
#pragma unroll
      for (int j = 0; j < 8; ++j) {
        float4 q;
        q.x = y0[4 * j]; q.y = y0[4 * j + 1]; q.z = y0[4 * j + 2]; q.w = y0[4 * j + 3];
        s4[j * 128 + lid] = q;
      }
#pragma unroll
      for (int j = 0; j < 8; ++j) {
        float4 q;
        q.x = y1[4 * j]; q.y = y1[4 * j + 1]; q.z = y1[4 * j + 2]; q.w = y1[4 * j + 3];
        s4[(8 + j) * 128 + lid] = q;
      }
    }
    __syncthreads();
    if (rh == 0) {
#pragma unroll
      for (int j = 0; j < 8; ++j) {
        float4 q = s4[j * 128 + lid];
        y0[4 * j] += q.x; y0[4 * j + 1] += q.y; y0[4 * j + 2] += q.z; y0[4 * j + 3] += q.w;
      }
#pragma unroll
      for (int j = 0; j < 8; ++j) {
        float4 q = s4[(8 + j) * 128 + lid];
        y1[4 * j] += q.x; y1[4 * j + 1] += q.y; y1[4 * j + 2] += q.z; y1[4 * j + 3] += q.w;
      }
      if (usePart) {
        float4* yp0 = reinterpret_cast<float4*>(
            ypart + (((size_t)b * kChunks + chunk) * kC + cp) * kD + seg * 32);
        float4* yp1 = reinterpret_cast<float4*>(
            ypart + (((size_t)b * kChunks + chunk) * kC + cp + 16) * kD + seg * 32);
#pragma unroll
        for (int j = 0; j < 8; ++j) {
          float4 q;
          q.x = y0[4 * j]; q.y = y0[4 * j + 1]; q.z = y0[4 * j + 2]; q.w = y0[4 * j + 3];
          yp0[j] = q;
          q.x = y1[4 * j]; q.y = y1[4 * j + 1]; q.z = y1[4 * j + 2]; q.w = y1[4 * j + 3];
          yp1[j] = q;
        }
      } else {
        float* yp0 = y + ((size_t)(b * kC + cp)) * kD + seg * 32;
        float* yp1 = y + ((size_t)(b * kC + cp + 16)) * kD + seg * 32;
#pragma unroll
        for (int i = 0; i < 32; ++i) { atomicAdd(yp0 + i, y0[i]); atomicAdd(yp1 + i, y1[i]); }
      }
    }
    if (t < 32) {
      float s = 0.f;
#pragma unroll
      for (int j = 0; j < 8; ++j) s += csL[j][t];
      if (usePart) cspart[((size_t)b * kChunks + chunk) * kC + t] = s;
      else atomicAdd(csum + b * kC + t, s);
    }
  }
}

// ---- k_mha2: fused qkv projection + scores + softmax + ctx. grid (B, HEADS).
__global__ __launch_bounds__(256) void k_mha2(
    const float* __restrict__ routed, const float* __restrict__ Wq,
    const float* __restrict__ bq, const float* __restrict__ Wk,
    const float* __restrict__ bk, const float* __restrict__ Wvp,
    const float* __restrict__ bvp, float* __restrict__ ctx) {
  const int b = blockIdx.x, head = blockIdx.y, t = threadIdx.x;
  __shared__ float rL[kC * kH];          // 8 KB
  __shared__ float WqL[kH][kKD + 1];     // 16.25 KB each, padded
  __shared__ float WkL[kH][kKD + 1];
  __shared__ float WvL[kH][kKD + 1];
  __shared__ float qL[kC][kKD];
  __shared__ float kL[kC][kKD + 1];
  __shared__ float vL[kC][kKD];
  __shared__ float sc[kC][kC + 1];
#pragma unroll
  for (int i = 0; i < 8; ++i) rL[t + 256 * i] = routed[(size_t)b * kC * kH + t + 256 * i];
#pragma unroll
  for (int i = 0; i < 16; ++i) {
    const int e = t + 256 * i, hh = e >> 6, kk = e & 63;
    const size_t wi = ((size_t)hh * kHeads + head) * kKD + kk;
    WqL[hh][kk] = Wq[wi];
    WkL[hh][kk] = Wk[wi];
    WvL[hh][kk] = Wvp[wi];
  }
  __syncthreads();
#pragma unroll
  for (int i = 0; i < 8; ++i) {
    const int e = t + 256 * i, cc = e >> 6, kk = e & 63;
    float aq = bq[head * kKD + kk];
    float ak = bk[head * kKD + kk];
    float av = bvp[head * kKD + kk];
#pragma unroll 8
    for (int hh = 0; hh < kH; ++hh) {
      const float r = rL[cc * kH + hh];
      aq = fmaf(r, WqL[hh][kk], aq);
      ak = fmaf(r, WkL[hh][kk], ak);
      av = fmaf(r, WvL[hh][kk], av);
    }
    qL[cc][kk] = aq; kL[cc][kk] = ak; vL[cc][kk] = av;
  }
  __syncthreads();
#pragma unroll
  for (int i = 0; i < 4; ++i) {
    const int e = t + 256 * i, qc = e >> 5, kc = e & 31;
    float s = 0.f;
#pragma unroll 8
    for (int d = 0; d < kKD; ++d) s = fmaf(qL[qc][d], kL[kc][d], s);
    sc[qc][kc] = s * 0.125f;  // 1/sqrt(64)
  }
  __syncthreads();
  if (t < kC) {
    float m = -1e30f;
#pragma unroll
    for (int kc = 0; kc < kC; ++kc) m = fmaxf(m, sc[t][kc]);
    float ssum = 0.f;
#pragma unroll
    for (int kc = 0; kc < kC; ++kc) {
      const float e2 = __expf(sc[t][kc] - m);
      sc[t][kc] = e2;
      ssum += e2;
    }
    const float inv = 1.f / ssum;
#pragma unroll
    for (int kc = 0; kc < kC; ++kc) sc[t][kc] *= inv;
  }
  __syncthreads();
#pragma unroll
  for (int i = 0; i < 8; ++i) {
    const int e = t + 256 * i, qc = e >> 6, d = e & 63;
    float s = 0.f;
#pragma unroll 8
    for (int kc = 0; kc < kC; ++kc) s = fmaf(sc[qc][kc], vL[kc][d], s);
    ctx[(((size_t)b * kC + qc) * kHeads + head) * kKD + d] = s;
  }
}

// ---- k_final: out-proj + residual + LN + squash*gamma. Block = (b,c).
__global__ __launch_bounds__(256) void k_final(
    const float* __restrict__ ctx, const float* __restrict__ Wo,
    const float* __restrict__ bo, const float* __restrict__ routed,
    const float* __restrict__ ln_g, const float* __restrict__ ln_b,
    const float* __restrict__ gamma, float* __restrict__ out) {
  const int bc = blockIdx.x, t = threadIdx.x;
  const int w = t >> 6, h = t & 63;
  __shared__ float cL[kHeads * kKD];
  __shared__ float sL[4][kH];
  cL[t] = ctx[(size_t)bc * (kHeads * kKD) + t];
  __syncthreads();
  float acc = 0.f;
#pragma unroll 8
  for (int nd = w * 64; nd < (w + 1) * 64; ++nd)
    acc = fmaf(cL[nd], Wo[(size_t)nd * kH + h], acc);
  sL[w][h] = acc;
  __syncthreads();
  if (t < 64) {
    const float yv = sL[0][h] + sL[1][h] + sL[2][h] + sL[3][h] + bo[h] +
                     routed[(size_t)bc * kH + h];
    float mu = yv;
#pragma unroll
    for (int off = 32; off; off >>= 1) mu += __shfl_xor(mu, off, 64);
    mu *= (1.f / (float)kH);
    const float dv = yv - mu;
    float var = dv * dv;
#pragma unroll
    for (int off = 32; off; off >>= 1) var += __shfl_xor(var, off, 64);
    var *= (1.f / (float)kH);
    const float nrm = dv * rsqrtf(var + 1e-3f) * ln_g[h] + ln_b[h];
    float s2 = nrm * nrm;
#pragma unroll
    for (int off = 32; off; off >>= 1) s2 += __shfl_xor(s2, off, 64);
    const float scale = s2 / (1.f + s2) * rsqrtf(s2 + 1e-7f);
    out[(size_t)bc * kH + h] = scale * nrm * gamma[0];
  }
}

extern "C" void kernel_launch(void* const* d_in, const int* in_sizes, int n_in,
                              void* d_out, int out_size, void* d_ws, size_t ws_size,
                              hipStream_t stream) {
  (void)in_sizes; (void)n_in; (void)out_size;
  const float* x      = (const float*)d_in[0];
  const float* W      = (const float*)d_in[1];
  const float* b_caps = (const float*)d_in[2];
  const float* gamma  = (const float*)d_in[3];
  const float* Wq     = (const float*)d_in[4];
  const float* bq     = (const float*)d_in[5];
  const float* Wk     = (const float*)d_in[6];
  const float* bk     = (const float*)d_in[7];
  const float* Wv_in  = (const float*)d_in[8];
  const float* bv_in  = (const float*)d_in[9];
  const float* Wo     = (const float*)d_in[10];
  const float* bo     = (const float*)d_in[11];
  const float* ln_g   = (const float*)d_in[12];
  const float* ln_b   = (const float*)d_in[13];
  float* out = (float*)d_out;
  float* ws  = (float*)d_ws;

  float* xpart = ws + OFF_XPART;
  float* v     = ws + OFF_V;
  float* Wv    = ws + OFF_WV;
  float* bv    = ws + OFF_BV;
  float* y     = ws + OFF_Y;
  float* cs    = ws + OFF_CS;
  float* ctx   = ws + OFF_CTX;
  float* csp   = ws + OFF_CSP;
  float* yp    = ws + OFF_YP;

  const int usePart = (ws_size >= WS_NEED_PARTIAL) ? 1 : 0;

  k_xpart<<<dim3(kB, 16), 256, 0, stream>>>(x, xpart);
  k_sv<<<kB * kC, 256, 0, stream>>>(W, b_caps, xpart, y, cs, yp, csp, v, Wv, bv,
                                    /*mode=*/0, /*computeWv=*/1, /*accWv=*/0, 0);

  if (!usePart) {
    hipMemsetAsync(y, 0, (size_t)kB * kC * kD * sizeof(float), stream);
    hipMemsetAsync(cs, 0, (size_t)kB * kC * sizeof(float), stream);
  }
  k_route<<<dim3(kB, kChunks), 256, 0, stream>>>(x, Wv, bv, y, cs, yp, csp, usePart);
  k_sv<<<kB * kC, 256, 0, stream>>>(W, b_caps, xpart, y, cs, yp, csp, v, Wv, bv,
                                    /*mode=*/1, /*computeWv=*/1, /*accWv=*/1,
                                    usePart ? kChunks : 0);

  if (!usePart) {
    hipMemsetAsync(y, 0, (size_t)kB * kC * kD * sizeof(float), stream);
    hipMemsetAsync(cs, 0, (size_t)kB * kC * sizeof(float), stream);
  }
  k_route<<<dim3(kB, kChunks), 256, 0, stream>>>(x, Wv, bv, y, cs, yp, csp, usePart);
  k_sv<<<kB * kC, 256, 0, stream>>>(W, b_caps, xpart, y, cs, yp, csp, v, Wv, bv,
                                    /*mode=*/1, /*computeWv=*/0, /*accWv=*/0,
                                    usePart ? kChunks : 0);

  k_mha2<<<dim3(kB, kHeads), 256, 0, stream>>>(v, Wq, bq, Wk, bk, Wv_in, bv_in, ctx);
  k_final<<<kB * kC, 256, 0, stream>>>(ctx, Wo, bo, v, ln_g, ln_b, gamma, out);
}

// Round 7
// 189.221 us; speedup vs baseline: 4.7260x; 1.2634x over previous
//
#include <hip/hip_runtime.h>
#include <cstddef>

typedef _Float16 f16;
typedef __attribute__((ext_vector_type(8))) _Float16 f16x8;
typedef __attribute__((ext_vector_type(4))) float f32x4;

namespace {
constexpr int kB = 16;
constexpr int kN = 2048;
constexpr int kD = 256;   // D_IN
constexpr int kC = 32;
constexpr int kH = 64;
constexpr int kHeads = 4;
constexpr int kKD = 64;
constexpr int kChunks = 32;                  // n-chunks per b
constexpr int kRows = kN / kChunks;          // 64 rows per chunk

// workspace offsets (floats)
constexpr size_t OFF_XPART = 0;                       // [B,16,D]          65536
constexpr size_t OFF_V     = OFF_XPART + 65536;       // [B,C,H]           32768
constexpr size_t OFF_WV    = OFF_V + 32768;           // [B,C,D] fp32     131072
constexpr size_t OFF_BV    = OFF_WV + 131072;         // [B,C]               512
constexpr size_t OFF_Y     = OFF_BV + 512;            // [B,C,D] (atomic) 131072
constexpr size_t OFF_CS    = OFF_Y + 131072;          // [B,C]               512
constexpr size_t OFF_CTX   = OFF_CS + 512;            // [B,C,HEADS,KD]   524288
constexpr size_t OFF_XF16  = OFF_CTX + 524288;        // [B,N,D] f16 -> 4194304 floats
constexpr size_t OFF_WVH   = OFF_XF16 + 4194304;      // [B,C,D] f16 ->   65536 floats
constexpr size_t OFF_CSP   = OFF_WVH + 65536;         // [B,chunks,C]      16384
constexpr size_t OFF_YP    = OFF_CSP + 16384;         // [B,chunks,C,D]  4194304
constexpr size_t WS_NEED_PARTIAL = (OFF_YP + 4194304) * sizeof(float);
}  // namespace

// ---- k_xpart: column sums of x per 128-row chunk + emit fp16 copy of x.
__global__ __launch_bounds__(256) void k_xpart(const float* __restrict__ x,
                                               float* __restrict__ xpart,
                                               f16* __restrict__ xh) {
  const int b = blockIdx.x, j = blockIdx.y, d = threadIdx.x;
  const size_t base = ((size_t)b * kN + (size_t)j * 128) * kD + d;
  const float* xp = x + base;
  f16* xo = xh + base;
  float s = 0.f;
#pragma unroll 4
  for (int n = 0; n < 128; ++n) {
    const float v = xp[(size_t)n * kD];
    s += v;
    xo[(size_t)n * kD] = (f16)v;
  }
  xpart[((size_t)b * 16 + j) * kD + d] = s;
}

// ---- k_sv: s = y·W[c] + cs*b_caps[c]; v = squash(s); optional Wv (+)= W[c]·v (fp32 + fp16 copy)
__global__ __launch_bounds__(256) void k_sv(
    const float* __restrict__ W, const float* __restrict__ b_caps,
    const float* __restrict__ xpart, const float* __restrict__ y,
    const float* __restrict__ csum, const float* __restrict__ ypart,
    const float* __restrict__ cspart, float* __restrict__ v,
    float* __restrict__ Wv, f16* __restrict__ Wvh, float* __restrict__ bv,
    const int mode, const int computeWv, const int accWv, const int npart) {
  const int bc = blockIdx.x, b = bc >> 5, c = bc & 31;
  const int t = threadIdx.x;
  const int w = t >> 6, h = t & 63;
  __shared__ float yL[kD];
  __shared__ float sL[4][kH];
  __shared__ float vL[kH];
  __shared__ float csLs;

  if (mode == 0) {
    float s = 0.f;
#pragma unroll
    for (int j = 0; j < 16; ++j) s += xpart[((size_t)b * 16 + j) * kD + t];
    yL[t] = s * (1.f / (float)kC);
    if (t == 0) csLs = (float)kN / (float)kC;
  } else if (npart > 0) {
    float s = 0.f;
#pragma unroll 8
    for (int ch = 0; ch < kChunks; ++ch)
      s += ypart[(((size_t)b * kChunks + ch) * kC + c) * kD + t];
    yL[t] = s;
    if (t < 32) {
      float cs_ = cspart[((size_t)b * kChunks + t) * kC + c];
#pragma unroll
      for (int off = 16; off; off >>= 1) cs_ += __shfl_xor(cs_, off, 64);
      if (t == 0) csLs = cs_;
    }
  } else {
    yL[t] = y[(size_t)bc * kD + t];
    if (t == 0) csLs = csum[bc];
  }
  __syncthreads();

  const float* Wc = W + (size_t)c * kD * kH;
  {
    float acc = 0.f;
#pragma unroll 8
    for (int d = w * 64; d < (w + 1) * 64; ++d)
      acc = fmaf(yL[d], Wc[(size_t)d * kH + h], acc);
    sL[w][h] = acc;
  }
  __syncthreads();

  if (t < 64) {
    const float bch = b_caps[c * kH + h];
    float s = sL[0][h] + sL[1][h] + sL[2][h] + sL[3][h] + csLs * bch;
    float s2 = s * s;
#pragma unroll
    for (int off = 32; off; off >>= 1) s2 += __shfl_xor(s2, off, 64);
    const float scale = s2 / (1.f + s2) * rsqrtf(s2 + 1e-7f);
    const float vh = scale * s;
    v[(size_t)bc * kH + h] = vh;
    vL[h] = vh;
    if (computeWv) {
      float bvp = bch * vh;
#pragma unroll
      for (int off = 32; off; off >>= 1) bvp += __shfl_xor(bvp, off, 64);
      if (h == 0) bv[bc] = accWv ? (bv[bc] + bvp) : bvp;
    }
  }
  __syncthreads();
  if (computeWv) {
    float acc = 0.f;
    const float* Wrow = Wc + (size_t)t * kH;
#pragma unroll 8
    for (int hh = 0; hh < kH; ++hh) acc = fmaf(Wrow[hh], vL[hh], acc);
    const size_t idx = (size_t)bc * kD + t;
    const float nv = accWv ? (Wv[idx] + acc) : acc;
    Wv[idx] = nv;
    Wvh[idx] = (f16)nv;
  }
}

// ---- k_route (MFMA): block = (b, 64-row chunk), 4 waves.
// GEMM1: logits[r][c] = x_f16[r]·Wv_f16[c] via mfma_f32_16x16x32_f16, frags from global.
// softmax (fp32) -> pT fp16. GEMM2: Y[c][d] = P^T·x from LDS (pT + transposed x tile).
__global__ __launch_bounds__(256) void k_route(
    const f16* __restrict__ xh, const f16* __restrict__ Wvh,
    const float* __restrict__ bv, float* __restrict__ y,
    float* __restrict__ csum, float* __restrict__ ypart,
    float* __restrict__ cspart, const int usePart) {
  const int b = blockIdx.x, chunk = blockIdx.y;
  const int t = threadIdx.x;
  const int lane = t & 63, w = t >> 6;
  const int l15 = lane & 15, q = lane >> 4;

  __shared__ __align__(16) f16 xsT[kD][kRows + 8];   // [256][72] transposed x, 36.9 KB
  __shared__ float aL[kRows][kC + 1];                // [64][33] logits, 8.4 KB
  __shared__ __align__(16) f16 pT[kC][kRows + 8];    // [32][72] P^T, 4.6 KB
  __shared__ float csL[8][kC];                       // 1 KB

  const int n0 = chunk * kRows;
  const float bvc = bv[b * kC + (t & 31)];

  // ---- stage xsT: wave w covers d in [w*64, w*64+64), lane = row.
  {
    const int r = lane, d0 = w * 64;
    const f16x8* gs = reinterpret_cast<const f16x8*>(
        xh + ((size_t)(b * kN + n0 + r)) * kD + d0);
#pragma unroll
    for (int jj = 0; jj < 8; ++jj) {
      f16x8 vv = gs[jj];
#pragma unroll
      for (int i = 0; i < 8; ++i) xsT[d0 + jj * 8 + i][r] = vv[i];
    }
  }

  // ---- GEMM1: wave w = row-tile mt (16 rows); caps split nt=0,1 (two accumulators).
  f32x4 acc0 = {0.f, 0.f, 0.f, 0.f}, acc1 = {0.f, 0.f, 0.f, 0.f};
  {
    const f16x8* Ar = reinterpret_cast<const f16x8*>(
        xh + ((size_t)(b * kN + n0 + w * 16 + l15)) * kD + q * 8);
    const f16x8* B0 = reinterpret_cast<const f16x8*>(
        Wvh + ((size_t)(b * kC + l15)) * kD + q * 8);
    const f16x8* B1 = reinterpret_cast<const f16x8*>(
        Wvh + ((size_t)(b * kC + 16 + l15)) * kD + q * 8);
#pragma unroll
    for (int ks = 0; ks < 8; ++ks) {
      f16x8 af = Ar[ks * 4];  // d = ks*32 + q*8 .. +7
      acc0 = __builtin_amdgcn_mfma_f32_16x16x32_f16(af, B0[ks * 4], acc0, 0, 0, 0);
      acc1 = __builtin_amdgcn_mfma_f32_16x16x32_f16(af, B1[ks * 4], acc1, 0, 0, 0);
    }
  }
  // D layout: col = lane&15 (cap-in-tile), row = q*4+reg (row-in-tile)
#pragma unroll
  for (int r = 0; r < 4; ++r) {
    aL[w * 16 + q * 4 + r][l15] = acc0[r];
    aL[w * 16 + q * 4 + r][16 + l15] = acc1[r];
  }
  __syncthreads();  // aL + xsT visible

  // ---- softmax over caps per row; thread (c = t&31, sg = t>>5) handles rows sg*8+k
  const int c = t & 31, sg = t >> 5;
  float csreg = 0.f;
#pragma unroll
  for (int k = 0; k < 8; ++k) {
    const int r = sg * 8 + k;
    float L = bvc + aL[r][c];
    float m = L;
#pragma unroll
    for (int off = 16; off; off >>= 1) m = fmaxf(m, __shfl_xor(m, off, 64));
    const float e = __expf(L - m);
    float ssum = e;
#pragma unroll
    for (int off = 16; off; off >>= 1) ssum += __shfl_xor(ssum, off, 64);
    const float p = e / ssum;
    pT[c][r] = (f16)p;
    csreg += p;
  }
  csL[sg][c] = csreg;
  __syncthreads();  // pT visible

  // ---- GEMM2: Y[cap][d] = sum_r P^T[cap][r]·x[r][d].  K=64 -> 2 mfma per tile.
  const int mt2 = w & 1;
  const int ntb = (w >> 1) * 8;
  const f16x8 a0 = *reinterpret_cast<const f16x8*>(&pT[mt2 * 16 + l15][q * 8]);
  const f16x8 a1 = *reinterpret_cast<const f16x8*>(&pT[mt2 * 16 + l15][32 + q * 8]);
  const int cap = mt2 * 16 + q * 4;
#pragma unroll
  for (int i = 0; i < 8; ++i) {
    const int d0 = (ntb + i) * 16;
    const f16x8 b0 = *reinterpret_cast<const f16x8*>(&xsT[d0 + l15][q * 8]);
    const f16x8 b1 = *reinterpret_cast<const f16x8*>(&xsT[d0 + l15][32 + q * 8]);
    f32x4 o = {0.f, 0.f, 0.f, 0.f};
    o = __builtin_amdgcn_mfma_f32_16x16x32_f16(a0, b0, o, 0, 0, 0);
    o = __builtin_amdgcn_mfma_f32_16x16x32_f16(a1, b1, o, 0, 0, 0);
    if (usePart) {
      float* dst = ypart + (((size_t)(b * kChunks + chunk)) * kC + cap) * kD + d0 + l15;
#pragma unroll
      for (int r = 0; r < 4; ++r) dst[(size_t)r * kD] = o[r];
    } else {
      float* dst = y + ((size_t)(b * kC + cap)) * kD + d0 + l15;
#pragma unroll
      for (int r = 0; r < 4; ++r) atomicAdd(dst + (size_t)r * kD, o[r]);
    }
  }
  if (t < 32) {
    float s = 0.f;
#pragma unroll
    for (int j = 0; j < 8; ++j) s += csL[j][t];
    if (usePart) cspart[((size_t)b * kChunks + chunk) * kC + t] = s;
    else atomicAdd(csum + b * kC + t, s);
  }
}

// ---- k_mha2: fused qkv projection + scores + softmax + ctx. grid (B, HEADS).
__global__ __launch_bounds__(256) void k_mha2(
    const float* __restrict__ routed, const float* __restrict__ Wq,
    const float* __restrict__ bq, const float* __restrict__ Wk,
    const float* __restrict__ bk, const float* __restrict__ Wvp,
    const float* __restrict__ bvp, float* __restrict__ ctx) {
  const int b = blockIdx.x, head = blockIdx.y, t = threadIdx.x;
  __shared__ float rL[kC * kH];
  __shared__ float WqL[kH][kKD + 1];
  __shared__ float WkL[kH][kKD + 1];
  __shared__ float WvL[kH][kKD + 1];
  __shared__ float qL[kC][kKD];
  __shared__ float kL[kC][kKD + 1];
  __shared__ float vL[kC][kKD];
  __shared__ float sc[kC][kC + 1];
#pragma unroll
  for (int i = 0; i < 8; ++i) rL[t + 256 * i] = routed[(size_t)b * kC * kH + t + 256 * i];
#pragma unroll
  for (int i = 0; i < 16; ++i) {
    const int e = t + 256 * i, hh = e >> 6, kk = e & 63;
    const size_t wi = ((size_t)hh * kHeads + head) * kKD + kk;
    WqL[hh][kk] = Wq[wi];
    WkL[hh][kk] = Wk[wi];
    WvL[hh][kk] = Wvp[wi];
  }
  __syncthreads();
#pragma unroll
  for (int i = 0; i < 8; ++i) {
    const int e = t + 256 * i, cc = e >> 6, kk = e & 63;
    float aq = bq[head * kKD + kk];
    float ak = bk[head * kKD + kk];
    float av = bvp[head * kKD + kk];
#pragma unroll 8
    for (int hh = 0; hh < kH; ++hh) {
      const float r = rL[cc * kH + hh];
      aq = fmaf(r, WqL[hh][kk], aq);
      ak = fmaf(r, WkL[hh][kk], ak);
      av = fmaf(r, WvL[hh][kk], av);
    }
    qL[cc][kk] = aq; kL[cc][kk] = ak; vL[cc][kk] = av;
  }
  __syncthreads();
#pragma unroll
  for (int i = 0; i < 4; ++i) {
    const int e = t + 256 * i, qc = e >> 5, kc = e & 31;
    float s = 0.f;
#pragma unroll 8
    for (int d = 0; d < kKD; ++d) s = fmaf(qL[qc][d], kL[kc][d], s);
    sc[qc][kc] = s * 0.125f;
  }
  __syncthreads();
  if (t < kC) {
    float m = -1e30f;
#pragma unroll
    for (int kc = 0; kc < kC; ++kc) m = fmaxf(m, sc[t][kc]);
    float ssum = 0.f;
#pragma unroll
    for (int kc = 0; kc < kC; ++kc) {
      const float e2 = __expf(sc[t][kc] - m);
      sc[t][kc] = e2;
      ssum += e2;
    }
    const float inv = 1.f / ssum;
#pragma unroll
    for (int kc = 0; kc < kC; ++kc) sc[t][kc] *= inv;
  }
  __syncthreads();
#pragma unroll
  for (int i = 0; i < 8; ++i) {
    const int e = t + 256 * i, qc = e >> 6, d = e & 63;
    float s = 0.f;
#pragma unroll 8
    for (int kc = 0; kc < kC; ++kc) s = fmaf(sc[qc][kc], vL[kc][d], s);
    ctx[(((size_t)b * kC + qc) * kHeads + head) * kKD + d] = s;
  }
}

// ---- k_final: out-proj + residual + LN + squash*gamma. Block = (b,c).
__global__ __launch_bounds__(256) void k_final(
    const float* __restrict__ ctx, const float* __restrict__ Wo,
    const float* __restrict__ bo, const float* __restrict__ routed,
    const float* __restrict__ ln_g, const float* __restrict__ ln_b,
    const float* __restrict__ gamma, float* __restrict__ out) {
  const int bc = blockIdx.x, t = threadIdx.x;
  const int w = t >> 6, h = t & 63;
  __shared__ float cL[kHeads * kKD];
  __shared__ float sL[4][kH];
  cL[t] = ctx[(size_t)bc * (kHeads * kKD) + t];
  __syncthreads();
  float acc = 0.f;
#pragma unroll 8
  for (int nd = w * 64; nd < (w + 1) * 64; ++nd)
    acc = fmaf(cL[nd], Wo[(size_t)nd * kH + h], acc);
  sL[w][h] = acc;
  __syncthreads();
  if (t < 64) {
    const float yv = sL[0][h] + sL[1][h] + sL[2][h] + sL[3][h] + bo[h] +
                     routed[(size_t)bc * kH + h];
    float mu = yv;
#pragma unroll
    for (int off = 32; off; off >>= 1) mu += __shfl_xor(mu, off, 64);
    mu *= (1.f / (float)kH);
    const float dv = yv - mu;
    float var = dv * dv;
#pragma unroll
    for (int off = 32; off; off >>= 1) var += __shfl_xor(var, off, 64);
    var *= (1.f / (float)kH);
    const float nrm = dv * rsqrtf(var + 1e-3f) * ln_g[h] + ln_b[h];
    float s2 = nrm * nrm;
#pragma unroll
    for (int off = 32; off; off >>= 1) s2 += __shfl_xor(s2, off, 64);
    const float scale = s2 / (1.f + s2) * rsqrtf(s2 + 1e-7f);
    out[(size_t)bc * kH + h] = scale * nrm * gamma[0];
  }
}

extern "C" void kernel_launch(void* const* d_in, const int* in_sizes, int n_in,
                              void* d_out, int out_size, void* d_ws, size_t ws_size,
                              hipStream_t stream) {
  (void)in_sizes; (void)n_in; (void)out_size;
  const float* x      = (const float*)d_in[0];
  const float* W      = (const float*)d_in[1];
  const float* b_caps = (const float*)d_in[2];
  const float* gamma  = (const float*)d_in[3];
  const float* Wq     = (const float*)d_in[4];
  const float* bq     = (const float*)d_in[5];
  const float* Wk     = (const float*)d_in[6];
  const float* bk     = (const float*)d_in[7];
  const float* Wv_in  = (const float*)d_in[8];
  const float* bv_in  = (const float*)d_in[9];
  const float* Wo     = (const float*)d_in[10];
  const float* bo     = (const float*)d_in[11];
  const float* ln_g   = (const float*)d_in[12];
  const float* ln_b   = (const float*)d_in[13];
  float* out = (float*)d_out;
  float* ws  = (float*)d_ws;

  float* xpart = ws + OFF_XPART;
  float* v     = ws + OFF_V;
  float* Wv    = ws + OFF_WV;
  float* bv    = ws + OFF_BV;
  float* y     = ws + OFF_Y;
  float* cs    = ws + OFF_CS;
  float* ctx   = ws + OFF_CTX;
  f16*   xf16  = (f16*)(ws + OFF_XF16);
  f16*   wvh   = (f16*)(ws + OFF_WVH);
  float* csp   = ws + OFF_CSP;
  float* yp    = ws + OFF_YP;

  const int usePart = (ws_size >= WS_NEED_PARTIAL) ? 1 : 0;

  k_xpart<<<dim3(kB, 16), 256, 0, stream>>>(x, xpart, xf16);
  k_sv<<<kB * kC, 256, 0, stream>>>(W, b_caps, xpart, y, cs, yp, csp, v, Wv, wvh, bv,
                                    /*mode=*/0, /*computeWv=*/1, /*accWv=*/0, 0);

  if (!usePart) {
    hipMemsetAsync(y, 0, (size_t)kB * kC * kD * sizeof(float), stream);
    hipMemsetAsync(cs, 0, (size_t)kB * kC * sizeof(float), stream);
  }
  k_route<<<dim3(kB, kChunks), 256, 0, stream>>>(xf16, wvh, bv, y, cs, yp, csp, usePart);
  k_sv<<<kB * kC, 256, 0, stream>>>(W, b_caps, xpart, y, cs, yp, csp, v, Wv, wvh, bv,
                                    /*mode=*/1, /*computeWv=*/1, /*accWv=*/1,
                                    usePart ? kChunks : 0);

  if (!usePart) {
    hipMemsetAsync(y, 0, (size_t)kB * kC * kD * sizeof(float), stream);
    hipMemsetAsync(cs, 0, (size_t)kB * kC * sizeof(float), stream);
  }
  k_route<<<dim3(kB, kChunks), 256, 0, stream>>>(xf16, wvh, bv, y, cs, yp, csp, usePart);
  k_sv<<<kB * kC, 256, 0, stream>>>(W, b_caps, xpart, y, cs, yp, csp, v, Wv, wvh, bv,
                                    /*mode=*/1, /*computeWv=*/0, /*accWv=*/0,
                                    usePart ? kChunks : 0);

  k_mha2<<<dim3(kB, kHeads), 256, 0, stream>>>(v, Wq, bq, Wk, bk, Wv_in, bv_in, ctx);
  k_final<<<kB * kC, 256, 0, stream>>>(ctx, Wo, bo, v, ln_g, ln_b, gamma, out);
}

// Round 8
// 179.043 us; speedup vs baseline: 4.9947x; 1.0568x over previous
//
#include <hip/hip_runtime.h>
#include <cstddef>

typedef _Float16 f16;
typedef __attribute__((ext_vector_type(8))) _Float16 f16x8;
typedef __attribute__((ext_vector_type(4))) float f32x4;

namespace {
constexpr int kB = 16;
constexpr int kN = 2048;
constexpr int kD = 256;   // D_IN
constexpr int kC = 32;
constexpr int kH = 64;
constexpr int kHeads = 4;
constexpr int kKD = 64;
constexpr int kChunks = 32;                  // n-chunks per b
constexpr int kRows = kN / kChunks;          // 64 rows per chunk
constexpr int kXJ = 64;                      // xpart sub-chunks (32 rows each)

// workspace offsets (floats)
constexpr size_t OFF_XPART = 0;                       // [B,64,D]         262144
constexpr size_t OFF_V     = OFF_XPART + 262144;      // [B,C,H]           32768
constexpr size_t OFF_WV    = OFF_V + 32768;           // [B,C,D] fp32     131072
constexpr size_t OFF_BV    = OFF_WV + 131072;         // [B,C]               512
constexpr size_t OFF_Y     = OFF_BV + 512;            // [B,C,D] (atomic) 131072
constexpr size_t OFF_CS    = OFF_Y + 131072;          // [B,C]               512
constexpr size_t OFF_QKV   = OFF_CS + 512;            // [3,B,H,C,KD]     393216
constexpr size_t OFF_CTX   = OFF_QKV + 393216;        // [B,C,HEADS,KD]   524288
constexpr size_t OFF_XF16  = OFF_CTX + 524288;        // [B,N,D] f16     4194304
constexpr size_t OFF_WVH   = OFF_XF16 + 4194304;      // [B,C,D] f16       65536
constexpr size_t OFF_CSP   = OFF_WVH + 65536;         // [B,chunks,C]      16384
constexpr size_t OFF_YP    = OFF_CSP + 16384;         // [B,chunks,C,D]  4194304
constexpr size_t WS_NEED_PARTIAL = (OFF_YP + 4194304) * sizeof(float);
}  // namespace

// ---- k_xpart: column sums of x per 32-row chunk + emit fp16 copy of x.
// 1024 blocks (4/CU) for latency hiding.
__global__ __launch_bounds__(256) void k_xpart(const float* __restrict__ x,
                                               float* __restrict__ xpart,
                                               f16* __restrict__ xh) {
  const int b = blockIdx.x, j = blockIdx.y, d = threadIdx.x;
  const size_t base = ((size_t)b * kN + (size_t)j * 32) * kD + d;
  const float* xp = x + base;
  f16* xo = xh + base;
  float s = 0.f;
#pragma unroll
  for (int n = 0; n < 32; ++n) {
    const float v = xp[(size_t)n * kD];
    s += v;
    xo[(size_t)n * kD] = (f16)v;
  }
  xpart[((size_t)b * kXJ + j) * kD + d] = s;
}

// ---- k_sv: s = y·W[c] + cs*b_caps[c]; v = squash(s); optional Wv (+)= W[c]·v (fp32 + fp16 copy)
__global__ __launch_bounds__(256) void k_sv(
    const float* __restrict__ W, const float* __restrict__ b_caps,
    const float* __restrict__ xpart, const float* __restrict__ y,
    const float* __restrict__ csum, const float* __restrict__ ypart,
    const float* __restrict__ cspart, float* __restrict__ v,
    float* __restrict__ Wv, f16* __restrict__ Wvh, float* __restrict__ bv,
    const int mode, const int computeWv, const int accWv, const int npart) {
  const int bc = blockIdx.x, b = bc >> 5, c = bc & 31;
  const int t = threadIdx.x;
  const int w = t >> 6, h = t & 63;
  __shared__ float yL[kD];
  __shared__ float sL[4][kH];
  __shared__ float vL[kH];
  __shared__ float csLs;

  if (mode == 0) {
    float s = 0.f;
#pragma unroll 8
    for (int j = 0; j < kXJ; ++j) s += xpart[((size_t)b * kXJ + j) * kD + t];
    yL[t] = s * (1.f / (float)kC);
    if (t == 0) csLs = (float)kN / (float)kC;
  } else if (npart > 0) {
    float s = 0.f;
#pragma unroll 8
    for (int ch = 0; ch < kChunks; ++ch)
      s += ypart[(((size_t)b * kChunks + ch) * kC + c) * kD + t];
    yL[t] = s;
    if (t < 32) {
      float cs_ = cspart[((size_t)b * kChunks + t) * kC + c];
#pragma unroll
      for (int off = 16; off; off >>= 1) cs_ += __shfl_xor(cs_, off, 64);
      if (t == 0) csLs = cs_;
    }
  } else {
    yL[t] = y[(size_t)bc * kD + t];
    if (t == 0) csLs = csum[bc];
  }
  __syncthreads();

  const float* Wc = W + (size_t)c * kD * kH;
  {
    float acc = 0.f;
#pragma unroll 8
    for (int d = w * 64; d < (w + 1) * 64; ++d)
      acc = fmaf(yL[d], Wc[(size_t)d * kH + h], acc);
    sL[w][h] = acc;
  }
  __syncthreads();

  if (t < 64) {
    const float bch = b_caps[c * kH + h];
    float s = sL[0][h] + sL[1][h] + sL[2][h] + sL[3][h] + csLs * bch;
    float s2 = s * s;
#pragma unroll
    for (int off = 32; off; off >>= 1) s2 += __shfl_xor(s2, off, 64);
    const float scale = s2 / (1.f + s2) * rsqrtf(s2 + 1e-7f);
    const float vh = scale * s;
    v[(size_t)bc * kH + h] = vh;
    vL[h] = vh;
    if (computeWv) {
      float bvp = bch * vh;
#pragma unroll
      for (int off = 32; off; off >>= 1) bvp += __shfl_xor(bvp, off, 64);
      if (h == 0) bv[bc] = accWv ? (bv[bc] + bvp) : bvp;
    }
  }
  __syncthreads();
  if (computeWv) {
    float acc = 0.f;
    const float* Wrow = Wc + (size_t)t * kH;
#pragma unroll 8
    for (int hh = 0; hh < kH; ++hh) acc = fmaf(Wrow[hh], vL[hh], acc);
    const size_t idx = (size_t)bc * kD + t;
    const float nv = accWv ? (Wv[idx] + acc) : acc;
    Wv[idx] = nv;
    Wvh[idx] = (f16)nv;
  }
}

// ---- k_route (MFMA): block = (b, 64-row chunk), 4 waves.
// GEMM1: logits = x_f16·Wv_f16^T via mfma_f32_16x16x32_f16; A-frags from global,
// and the SAME frags are transposed into LDS xsT for GEMM2 (q-rotated write order:
// naive order puts all 4 q-groups on identical banks since 8q*stride≡0 mod 32).
// softmax fp32 -> pT fp16. GEMM2: Y = P^T·x from LDS.
__global__ __launch_bounds__(256) void k_route(
    const f16* __restrict__ xh, const f16* __restrict__ Wvh,
    const float* __restrict__ bv, float* __restrict__ y,
    float* __restrict__ csum, float* __restrict__ ypart,
    float* __restrict__ cspart, const int usePart) {
  const int b = blockIdx.x, chunk = blockIdx.y;
  const int t = threadIdx.x;
  const int lane = t & 63, w = t >> 6;
  const int l15 = lane & 15, q = lane >> 4;

  __shared__ __align__(16) f16 xsT[kD][kRows + 8];   // [256][72] transposed x
  __shared__ float aL[kRows][kC + 4];                // [64][36] logits
  __shared__ __align__(16) f16 pT[kC][kRows + 8];    // [32][72] P^T
  __shared__ float csL[8][kC];

  const int n0 = chunk * kRows;
  const float bvc = bv[b * kC + (t & 31)];

  // ---- GEMM1 + transpose staging from A-frags
  f32x4 acc0 = {0.f, 0.f, 0.f, 0.f}, acc1 = {0.f, 0.f, 0.f, 0.f};
  {
    const int row = w * 16 + l15;
    const f16x8* Ar = reinterpret_cast<const f16x8*>(
        xh + ((size_t)(b * kN + n0 + row)) * kD + q * 8);
    const f16x8* B0 = reinterpret_cast<const f16x8*>(
        Wvh + ((size_t)(b * kC + l15)) * kD + q * 8);
    const f16x8* B1 = reinterpret_cast<const f16x8*>(
        Wvh + ((size_t)(b * kC + 16 + l15)) * kD + q * 8);
#pragma unroll
    for (int ks = 0; ks < 8; ++ks) {
      f16x8 af = Ar[ks * 4];  // d = ks*32 + q*8 .. +7
      acc0 = __builtin_amdgcn_mfma_f32_16x16x32_f16(af, B0[ks * 4], acc0, 0, 0, 0);
      acc1 = __builtin_amdgcn_mfma_f32_16x16x32_f16(af, B1[ks * 4], acc1, 0, 0, 0);
      const int dbase = ks * 32 + q * 8;
#pragma unroll
      for (int i = 0; i < 8; ++i) {
        const int ii = (i + 2 * q) & 7;  // rotate: distinct banks across q-groups
        xsT[dbase + ii][row] = af[ii];
      }
    }
  }
  // D layout: col = lane&15 (cap-in-tile), row = q*4+reg (row-in-tile)
#pragma unroll
  for (int r = 0; r < 4; ++r) {
    aL[w * 16 + q * 4 + r][l15] = acc0[r];
    aL[w * 16 + q * 4 + r][16 + l15] = acc1[r];
  }
  __syncthreads();  // aL + xsT visible

  // ---- softmax over caps per row; thread (c = t&31, sg = t>>5) handles rows sg*8+k
  const int c = t & 31, sg = t >> 5;
  float csreg = 0.f;
#pragma unroll
  for (int k = 0; k < 8; ++k) {
    const int r = sg * 8 + k;
    float L = bvc + aL[r][c];
    float m = L;
#pragma unroll
    for (int off = 16; off; off >>= 1) m = fmaxf(m, __shfl_xor(m, off, 64));
    const float e = __expf(L - m);
    float ssum = e;
#pragma unroll
    for (int off = 16; off; off >>= 1) ssum += __shfl_xor(ssum, off, 64);
    const float p = e / ssum;
    pT[c][r] = (f16)p;
    csreg += p;
  }
  csL[sg][c] = csreg;
  __syncthreads();  // pT visible

  // ---- GEMM2: Y[cap][d] = sum_r P^T[cap][r]·x[r][d].  K=64 -> 2 mfma per tile.
  const int mt2 = w & 1;
  const int ntb = (w >> 1) * 8;
  const f16x8 a0 = *reinterpret_cast<const f16x8*>(&pT[mt2 * 16 + l15][q * 8]);
  const f16x8 a1 = *reinterpret_cast<const f16x8*>(&pT[mt2 * 16 + l15][32 + q * 8]);
  const int cap = mt2 * 16 + q * 4;
#pragma unroll
  for (int i = 0; i < 8; ++i) {
    const int d0 = (ntb + i) * 16;
    const f16x8 b0 = *reinterpret_cast<const f16x8*>(&xsT[d0 + l15][q * 8]);
    const f16x8 b1 = *reinterpret_cast<const f16x8*>(&xsT[d0 + l15][32 + q * 8]);
    f32x4 o = {0.f, 0.f, 0.f, 0.f};
    o = __builtin_amdgcn_mfma_f32_16x16x32_f16(a0, b0, o, 0, 0, 0);
    o = __builtin_amdgcn_mfma_f32_16x16x32_f16(a1, b1, o, 0, 0, 0);
    if (usePart) {
      float* dst = ypart + (((size_t)(b * kChunks + chunk)) * kC + cap) * kD + d0 + l15;
#pragma unroll
      for (int r = 0; r < 4; ++r) dst[(size_t)r * kD] = o[r];
    } else {
      float* dst = y + ((size_t)(b * kC + cap)) * kD + d0 + l15;
#pragma unroll
      for (int r = 0; r < 4; ++r) atomicAdd(dst + (size_t)r * kD, o[r]);
    }
  }
  if (t < 32) {
    float s = 0.f;
#pragma unroll
    for (int j = 0; j < 8; ++j) s += csL[j][t];
    if (usePart) cspart[((size_t)b * kChunks + chunk) * kC + t] = s;
    else atomicAdd(csum + b * kC + t, s);
  }
}

// ---- k_qkv: one projection per block, grid (B, HEADS, 3). W read direct from
// global (coalesced, L2-resident); routed staged in LDS (broadcast reads).
__global__ __launch_bounds__(256) void k_qkv(
    const float* __restrict__ routed, const float* __restrict__ Wq,
    const float* __restrict__ bq, const float* __restrict__ Wk,
    const float* __restrict__ bk, const float* __restrict__ Wvp,
    const float* __restrict__ bvp, float* __restrict__ qkv) {
  const int b = blockIdx.x, head = blockIdx.y, which = blockIdx.z;
  const int t = threadIdx.x;
  const int kk = t & 63, w = t >> 6;
  const float* Wsrc = (which == 0) ? Wq : (which == 1) ? Wk : Wvp;
  const float* bsrc = (which == 0) ? bq : (which == 1) ? bk : bvp;
  __shared__ float rL[kC * kH];
#pragma unroll
  for (int i = 0; i < 8; ++i) rL[t + 256 * i] = routed[(size_t)b * kC * kH + t + 256 * i];
  __syncthreads();
  // wave w handles caps cc = w + 4i (same cc across the wave -> rL broadcast)
  float acc[8];
  const float bb = bsrc[head * kKD + kk];
#pragma unroll
  for (int i = 0; i < 8; ++i) acc[i] = bb;
#pragma unroll 4
  for (int hh = 0; hh < kH; ++hh) {
    const float wv = Wsrc[((size_t)hh * kHeads + head) * kKD + kk];
#pragma unroll
    for (int i = 0; i < 8; ++i)
      acc[i] = fmaf(rL[(w + 4 * i) * kH + hh], wv, acc[i]);
  }
#pragma unroll
  for (int i = 0; i < 8; ++i) {
    const int cc = w + 4 * i;
    qkv[((((size_t)which * kB + b) * kHeads + head) * kC + cc) * kKD + kk] = acc[i];
  }
}

// ---- k_attn2: scores + softmax + ctx from staged q/k/v. grid (B, HEADS).
__global__ __launch_bounds__(256) void k_attn2(const float* __restrict__ qkv,
                                               float* __restrict__ ctx) {
  const int b = blockIdx.x, head = blockIdx.y, t = threadIdx.x;
  constexpr size_t kWhichStride = (size_t)kB * kHeads * kC * kKD;
  const size_t base = ((size_t)b * kHeads + head) * kC * kKD;
  __shared__ float qL[kC][kKD];
  __shared__ float kL[kC][kKD + 1];
  __shared__ float vL[kC][kKD];
  __shared__ float sc[kC][kC + 1];
#pragma unroll
  for (int i = 0; i < 8; ++i) {
    const int e = t + 256 * i, cc = e >> 6, kk = e & 63;
    qL[cc][kk] = qkv[base + e];
    kL[cc][kk] = qkv[base + kWhichStride + e];
    vL[cc][kk] = qkv[base + 2 * kWhichStride + e];
  }
  __syncthreads();
#pragma unroll
  for (int i = 0; i < 4; ++i) {
    const int e = t + 256 * i, qc = e >> 5, kc = e & 31;
    float s = 0.f;
#pragma unroll 8
    for (int d = 0; d < kKD; ++d) s = fmaf(qL[qc][d], kL[kc][d], s);
    sc[qc][kc] = s * 0.125f;
  }
  __syncthreads();
  if (t < kC) {
    float m = -1e30f;
#pragma unroll
    for (int kc = 0; kc < kC; ++kc) m = fmaxf(m, sc[t][kc]);
    float ssum = 0.f;
#pragma unroll
    for (int kc = 0; kc < kC; ++kc) {
      const float e2 = __expf(sc[t][kc] - m);
      sc[t][kc] = e2;
      ssum += e2;
    }
    const float inv = 1.f / ssum;
#pragma unroll
    for (int kc = 0; kc < kC; ++kc) sc[t][kc] *= inv;
  }
  __syncthreads();
#pragma unroll
  for (int i = 0; i < 8; ++i) {
    const int e = t + 256 * i, qc = e >> 6, d = e & 63;
    float s = 0.f;
#pragma unroll 8
    for (int kc = 0; kc < kC; ++kc) s = fmaf(sc[qc][kc], vL[kc][d], s);
    ctx[(((size_t)b * kC + qc) * kHeads + head) * kKD + d] = s;
  }
}

// ---- k_final: out-proj + residual + LN + squash*gamma. Block = (b,c).
__global__ __launch_bounds__(256) void k_final(
    const float* __restrict__ ctx, const float* __restrict__ Wo,
    const float* __restrict__ bo, const float* __restrict__ routed,
    const float* __restrict__ ln_g, const float* __restrict__ ln_b,
    const float* __restrict__ gamma, float* __restrict__ out) {
  const int bc = blockIdx.x, t = threadIdx.x;
  const int w = t >> 6, h = t & 63;
  __shared__ float cL[kHeads * kKD];
  __shared__ float sL[4][kH];
  cL[t] = ctx[(size_t)bc * (kHeads * kKD) + t];
  __syncthreads();
  float acc = 0.f;
#pragma unroll 8
  for (int nd = w * 64; nd < (w + 1) * 64; ++nd)
    acc = fmaf(cL[nd], Wo[(size_t)nd * kH + h], acc);
  sL[w][h] = acc;
  __syncthreads();
  if (t < 64) {
    const float yv = sL[0][h] + sL[1][h] + sL[2][h] + sL[3][h] + bo[h] +
                     routed[(size_t)bc * kH + h];
    float mu = yv;
#pragma unroll
    for (int off = 32; off; off >>= 1) mu += __shfl_xor(mu, off, 64);
    mu *= (1.f / (float)kH);
    const float dv = yv - mu;
    float var = dv * dv;
#pragma unroll
    for (int off = 32; off; off >>= 1) var += __shfl_xor(var, off, 64);
    var *= (1.f / (float)kH);
    const float nrm = dv * rsqrtf(var + 1e-3f) * ln_g[h] + ln_b[h];
    float s2 = nrm * nrm;
#pragma unroll
    for (int off = 32; off; off >>= 1) s2 += __shfl_xor(s2, off, 64);
    const float scale = s2 / (1.f + s2) * rsqrtf(s2 + 1e-7f);
    out[(size_t)bc * kH + h] = scale * nrm * gamma[0];
  }
}

extern "C" void kernel_launch(void* const* d_in, const int* in_sizes, int n_in,
                              void* d_out, int out_size, void* d_ws, size_t ws_size,
                              hipStream_t stream) {
  (void)in_sizes; (void)n_in; (void)out_size;
  const float* x      = (const float*)d_in[0];
  const float* W      = (const float*)d_in[1];
  const float* b_caps = (const float*)d_in[2];
  const float* gamma  = (const float*)d_in[3];
  const float* Wq     = (const float*)d_in[4];
  const float* bq     = (const float*)d_in[5];
  const float* Wk     = (const float*)d_in[6];
  const float* bk     = (const float*)d_in[7];
  const float* Wv_in  = (const float*)d_in[8];
  const float* bv_in  = (const float*)d_in[9];
  const float* Wo     = (const float*)d_in[10];
  const float* bo     = (const float*)d_in[11];
  const float* ln_g   = (const float*)d_in[12];
  const float* ln_b   = (const float*)d_in[13];
  float* out = (float*)d_out;
  float* ws  = (float*)d_ws;

  float* xpart = ws + OFF_XPART;
  float* v     = ws + OFF_V;
  float* Wv    = ws + OFF_WV;
  float* bv    = ws + OFF_BV;
  float* y     = ws + OFF_Y;
  float* cs    = ws + OFF_CS;
  float* qkv   = ws + OFF_QKV;
  float* ctx   = ws + OFF_CTX;
  f16*   xf16  = (f16*)(ws + OFF_XF16);
  f16*   wvh   = (f16*)(ws + OFF_WVH);
  float* csp   = ws + OFF_CSP;
  float* yp    = ws + OFF_YP;

  const int usePart = (ws_size >= WS_NEED_PARTIAL) ? 1 : 0;

  k_xpart<<<dim3(kB, kXJ), 256, 0, stream>>>(x, xpart, xf16);
  k_sv<<<kB * kC, 256, 0, stream>>>(W, b_caps, xpart, y, cs, yp, csp, v, Wv, wvh, bv,
                                    /*mode=*/0, /*computeWv=*/1, /*accWv=*/0, 0);

  if (!usePart) {
    hipMemsetAsync(y, 0, (size_t)kB * kC * kD * sizeof(float), stream);
    hipMemsetAsync(cs, 0, (size_t)kB * kC * sizeof(float), stream);
  }
  k_route<<<dim3(kB, kChunks), 256, 0, stream>>>(xf16, wvh, bv, y, cs, yp, csp, usePart);
  k_sv<<<kB * kC, 256, 0, stream>>>(W, b_caps, xpart, y, cs, yp, csp, v, Wv, wvh, bv,
                                    /*mode=*/1, /*computeWv=*/1, /*accWv=*/1,
                                    usePart ? kChunks : 0);

  if (!usePart) {
    hipMemsetAsync(y, 0, (size_t)kB * kC * kD * sizeof(float), stream);
    hipMemsetAsync(cs, 0, (size_t)kB * kC * sizeof(float), stream);
  }
  k_route<<<dim3(kB, kChunks), 256, 0, stream>>>(xf16, wvh, bv, y, cs, yp, csp, usePart);
  k_sv<<<kB * kC, 256, 0, stream>>>(W, b_caps, xpart, y, cs, yp, csp, v, Wv, wvh, bv,
                                    /*mode=*/1, /*computeWv=*/0, /*accWv=*/0,
                                    usePart ? kChunks : 0);

  k_qkv<<<dim3(kB, kHeads, 3), 256, 0, stream>>>(v, Wq, bq, Wk, bk, Wv_in, bv_in, qkv);
  k_attn2<<<dim3(kB, kHeads), 256, 0, stream>>>(qkv, ctx);
  k_final<<<kB * kC, 256, 0, stream>>>(ctx, Wo, bo, v, ln_g, ln_b, gamma, out);
}